// Round 12
// baseline (777.703 us; speedup 1.0000x reference)
//
#include <hip/hip_runtime.h>
#include <hip/hip_bf16.h>

typedef __attribute__((ext_vector_type(8))) _Float16 hfrag;
typedef __attribute__((ext_vector_type(4))) float ffrag;
typedef __attribute__((ext_vector_type(4))) _Float16 h4v;

// bucket = 128 consecutive nodes; supports N <= 131072 (hist arrays sized 1024)
#define BSH 7
#define LBS 128
#define NF 1024                // edge partitions; each block owns a PRIVATE output window
#define OPAD 800               // row stride of fragment-offset tables (> nbk max 782)
#define CONV_BLKS 384
#define ELC 2816               // per-bucket edge-list capacity (mean 1535, +33 sigma)

__device__ __forceinline__ float b2f_(unsigned short u) {
    return __uint_as_float(((unsigned)u) << 16);
}
__device__ __forceinline__ unsigned short f2b_(float v) {
    __hip_bfloat16 h = __float2bfloat16(v);   // RNE
    return *reinterpret_cast<unsigned short*>(&h);
}
__device__ __forceinline__ unsigned short f2h_(float v) {
    _Float16 h = (_Float16)v;                 // RNE
    return __builtin_bit_cast(unsigned short, h);
}
__device__ __forceinline__ float h2f_(unsigned short u) {
    _Float16 h = __builtin_bit_cast(_Float16, u);
    return (float)h;
}

__device__ __forceinline__ float loadF(const void* p, long long i, int isF32) {
    if (isF32) return ((const float*)p)[i];
    return b2f_(((const unsigned short*)p)[i]);
}

__device__ __forceinline__ float4 loadF4(const void* p, long long base, int i4, int isF32) {
    if (isF32) {
        return ((const float4*)((const float*)p + base))[i4];
    } else {
        ushort4 u = ((const ushort4*)((const unsigned short*)p + base))[i4];
        return make_float4(b2f_(u.x), b2f_(u.y), b2f_(u.z), b2f_(u.w));
    }
}

__device__ __forceinline__ void get_edge(const int* ei, int i64, int e, int E, int& s, int& d) {
    if (i64) { s = ei[2 * (long long)e]; d = ei[2 * (long long)E + 2 * (long long)e]; }
    else     { s = ei[e];                d = ei[(long long)E + e]; }
}

// batch-load 4 edges (srcs+dsts) with int4 vector loads; e0 multiple of 4
struct E4 { int s[4]; int d[4]; };
__device__ __forceinline__ E4 load4(const int* __restrict__ ei, int i64, int e0, int E) {
    E4 r;
    if (i64) {
        const int4* ps = (const int4*)(ei + 2 * (long long)e0);
        const int4* pd = (const int4*)(ei + 2 * (long long)E + 2 * (long long)e0);
        int4 a = ps[0], b = ps[1];
        int4 c = pd[0], d = pd[1];
        r.s[0] = a.x; r.s[1] = a.z; r.s[2] = b.x; r.s[3] = b.z;
        r.d[0] = c.x; r.d[1] = c.z; r.d[2] = d.x; r.d[3] = d.z;
    } else {
        int4 a = *(const int4*)(ei + e0);
        int4 c = *(const int4*)(ei + (long long)E + e0);
        r.s[0] = a.x; r.s[1] = a.y; r.s[2] = a.z; r.s[3] = a.w;
        r.d[0] = c.x; r.d[1] = c.y; r.d[2] = c.z; r.d[3] = c.w;
    }
    return r;
}

// exclusive scan of a[0..nEl) in LDS by ONE wave (lane = 0..63), chunked shuffle scan
__device__ __forceinline__ void wave_scan_excl(int* a, int nEl, int lane) {
    int run = 0;
    for (int base = 0; base < nEl; base += 64) {
        int i = base + lane;
        int orig = (i < nEl) ? a[i] : 0;
        int v = orig;
#pragma unroll
        for (int off = 1; off < 64; off <<= 1) {
            int u = __shfl_up(v, off);
            if (lane >= off) v += u;
        }
        if (i < nEl) a[i] = v - orig + run;
        run += __shfl(v, 63);
    }
}

// ---- S1 (single staging kernel, fully independent blocks):
//   blocks [0,NF): local bucket-sort of a PRIVATE contiguous edge slice into a
//     PRIVATE output window (LDS hist -> LDS scan -> local scatter).
//   block NF: dtype detect + flags + weight conversion + fp16 MFMA-fragment pack.
//   blocks > NF: x -> fp16 conversion (locally re-derived dtype flag). ----
__global__ __launch_bounds__(256) void k_stage(const void* __restrict__ x,
                                               const int* __restrict__ ei,
                                               const void* __restrict__ W1, const void* __restrict__ b1,
                                               const void* __restrict__ W2, const void* __restrict__ b2,
                                               int E, int N, int nbk, int EPB,
                                               int* __restrict__ flags, float* __restrict__ Wbuf,
                                               unsigned short* __restrict__ Wh1,
                                               unsigned short* __restrict__ Wh2,
                                               int* __restrict__ off_d, int* __restrict__ off_s,
                                               int* __restrict__ pdst,
                                               unsigned char* __restrict__ psrc,
                                               unsigned short* __restrict__ xh) {
    __shared__ int hd[800], hs[800], cd[800], cs[800];
    __shared__ int s_sane, s_zero;
    int tid = threadIdx.x;
    if (tid == 0) { s_sane = 0; s_zero = 0; }
    __syncthreads();
    const unsigned short* xu = (const unsigned short*)x;
    if (blockIdx.x == NF) {
        int sane = 0;
        for (int k = tid; k < 4096; k += 256) {
            float v = b2f_(xu[2 * k]);
            float a = fabsf(v);
            if (v == 0.0f || (a >= 9.3e-10f && a <= 1.1e9f)) sane++;
        }
        if (sane) atomicAdd(&s_sane, sane);
        int zero = 0;
        for (int k = tid; k < 1024; k += 256) if (ei[2 * k + 1] == 0) zero++;
        if (zero) atomicAdd(&s_zero, zero);
        __syncthreads();
        int f = (s_sane < 3000) ? 1 : 0;   // 1 = f32 input
        if (tid == 0) { flags[0] = f; flags[1] = (s_zero > 512) ? 1 : 0; }
        for (int i = tid; i < 4096; i += 256) Wbuf[i] = loadF(W1, i, f);
        if (tid < 64) Wbuf[4096 + tid] = loadF(b1, tid, f);
        for (int i = tid; i < 1024; i += 256) Wbuf[4160 + i] = loadF(W2, i, f);
        if (tid < 16) Wbuf[5184 + tid] = loadF(b2, tid, f);
        __syncthreads();
        // pack W1/W2 into fp16 MFMA B-fragment order
        for (int i = tid; i < 4096; i += 256) {
            int j = i & 7, m = (i >> 3) & 15, q = (i >> 7) & 3, kn = i >> 9;
            int kt = kn & 1, nt = kn >> 1;
            Wh1[i] = f2h_(Wbuf[(kt * 32 + q * 8 + j) * 64 + nt * 16 + m]);
        }
        for (int i = tid; i < 1024; i += 256) {
            int j = i & 7, m = (i >> 3) & 15, q = (i >> 7) & 3, kt = i >> 9;
            Wh2[i] = f2h_(Wbuf[4160 + (kt * 32 + q * 8 + j) * 16 + m]);
        }
        return;
    }
    if (blockIdx.x > NF) {
        // ---- conv block: local dtype re-derivation (L2-hot), then x->fp16 ----
        int cb = blockIdx.x - NF - 1;
        int sane = 0;
        for (int k = tid; k < 4096; k += 256) {
            float v = b2f_(xu[2 * k]);
            float a = fabsf(v);
            if (v == 0.0f || (a >= 9.3e-10f && a <= 1.1e9f)) sane++;
        }
        if (sane) atomicAdd(&s_sane, sane);
        __syncthreads();
        int f = (s_sane < 3000) ? 1 : 0;
        int n4 = N * 16;   // float4-groups
        int ctid = cb * 256 + tid;
        int stride = CONV_BLKS * 256 * 2;
        for (int i0 = ctid * 2; i0 < n4; i0 += stride) {
            float4 v0 = loadF4(x, 0, i0, f);
            float4 v1 = (i0 + 1 < n4) ? loadF4(x, 0, i0 + 1, f) : make_float4(0, 0, 0, 0);
            ushort4 o0, o1;
            o0.x = f2h_(v0.x); o0.y = f2h_(v0.y); o0.z = f2h_(v0.z); o0.w = f2h_(v0.w);
            o1.x = f2h_(v1.x); o1.y = f2h_(v1.y); o1.z = f2h_(v1.z); o1.w = f2h_(v1.w);
            ((ushort4*)xh)[i0] = o0;
            if (i0 + 1 < n4) ((ushort4*)xh)[i0 + 1] = o1;
        }
        return;
    }
    // ---- edge block fb: private slice [elo, ehi), private window [elo, elo+ecnt) ----
    int zero = 0;
    for (int k = tid; k < 1024; k += 256) if (ei[2 * k + 1] == 0) zero++;
    if (zero) atomicAdd(&s_zero, zero);
    for (int i = tid; i < 800; i += 256) { hd[i] = 0; hs[i] = 0; }
    __syncthreads();
    int i64 = (s_zero > 512) ? 1 : 0;
    int fb = blockIdx.x;
    int elo = fb * EPB;
    int ehi = min(elo + EPB, E);
    if (elo >= E) {    // empty slice: still publish (empty) fragment offsets
        for (int b = tid; b <= nbk; b += 256) {
            off_d[fb * OPAD + b] = E; off_s[fb * OPAD + b] = E;
        }
        return;
    }
    int ecnt = ehi - elo;
    // sweep 1: bucket histogram of the private slice
    for (int e0 = elo + tid * 4; e0 + 4 <= ehi; e0 += 1024) {
        E4 a = load4(ei, i64, e0, E);
#pragma unroll
        for (int u = 0; u < 4; ++u) {
            atomicAdd(&hd[a.d[u] >> BSH], 1);
            atomicAdd(&hs[a.s[u] >> BSH], 1);
        }
    }
    int rem = ecnt & 3, ebase = elo + (ecnt & ~3);
    if (tid < rem) {
        int s, d;
        get_edge(ei, i64, ebase + tid, E, s, d);
        atomicAdd(&hd[d >> BSH], 1);
        atomicAdd(&hs[s >> BSH], 1);
    }
    __syncthreads();
    if (tid < 64)       wave_scan_excl(hd, nbk, tid);
    else if (tid < 128) wave_scan_excl(hs, nbk, tid - 64);
    __syncthreads();
    // publish absolute fragment offsets + init private cursors
    for (int b = tid; b < nbk; b += 256) {
        int od = elo + hd[b], os = elo + hs[b];
        off_d[fb * OPAD + b] = od; cd[b] = od;
        off_s[fb * OPAD + b] = os; cs[b] = os;
    }
    if (tid == 0) { off_d[fb * OPAD + nbk] = elo + ecnt; off_s[fb * OPAD + nbk] = elo + ecnt; }
    __syncthreads();
    // sweep 2: scatter into the PRIVATE window (slice is L1/L2-hot from sweep 1)
    for (int e0 = elo + tid * 4; e0 + 4 <= ehi; e0 += 1024) {
        E4 a = load4(ei, i64, e0, E);
#pragma unroll
        for (int u = 0; u < 4; ++u) {
            int p = atomicAdd(&cd[a.d[u] >> BSH], 1);
            pdst[p] = (a.s[u] << BSH) | (a.d[u] & (LBS - 1));
            int q = atomicAdd(&cs[a.s[u] >> BSH], 1);
            psrc[q] = (unsigned char)(a.s[u] & (LBS - 1));
        }
    }
    if (tid < rem) {
        int s, d;
        get_edge(ei, i64, ebase + tid, E, s, d);
        int p = atomicAdd(&cd[d >> BSH], 1);
        pdst[p] = (s << BSH) | (d & (LBS - 1));
        int q = atomicAdd(&cs[s >> BSH], 1);
        psrc[q] = (unsigned char)(s & (LBS - 1));
    }
}

// ---- C2: per-node src degree via fragment GATHER -> dis = rsqrt(deg+1) ----
__global__ __launch_bounds__(256) void k_deg(const unsigned char* __restrict__ psrc,
                                             const int* __restrict__ off_s,
                                             float* __restrict__ dis, int N, int nbk) {
    __shared__ int h[LBS];
    int b = blockIdx.x, tid = threadIdx.x;
    if (tid < LBS) h[tid] = 0;
    __syncthreads();
    for (int fb = tid; fb < NF; fb += 256) {
        int o0 = off_s[fb * OPAD + b];
        int o1 = off_s[fb * OPAD + b + 1];
        for (int p = o0; p < o1; ++p) atomicAdd(&h[psrc[p]], 1);
    }
    __syncthreads();
    if (tid < LBS) {
        int node = b * LBS + tid;
        if (node < N) dis[node] = rsqrtf((float)h[tid] + 1.0f);
    }
}

// ---- C3: fused agg + dense per bucket (no CSR!):
//   phase 0: compact the bucket's dst-fragments into LDS elist
//   phase 1: edge-parallel gather xh[src] * dis[src] -> ds_add_f32 LDS accum
//   phase 2: finalize AGG = dd*(dd*x + accum) -> fp16 tile T
//   phase 3: per-wave barrier-free layer1+layer2 MFMA -> t2b ----
__global__ __launch_bounds__(512) void k_agg(const unsigned short* __restrict__ xh,
                                             const float* __restrict__ dis,
                                             const int* __restrict__ off_d,
                                             const int* __restrict__ pdst,
                                             const unsigned short* __restrict__ Wh1,
                                             const unsigned short* __restrict__ Wh2,
                                             const float* __restrict__ Wbuf,
                                             unsigned short* __restrict__ t2b, int N) {
    __shared__ int elist[ELC];
    __shared__ float acc[LBS * 68];          // stride 68: atomic bank-spread
    __shared__ __align__(16) unsigned short T[LBS * 72];
    __shared__ int s_cnt;
    int b = blockIdx.x, tid = threadIdx.x;
    if (tid == 0) s_cnt = 0;
    for (int i = tid; i < LBS * 68; i += 512) acc[i] = 0.f;
    __syncthreads();
    // phase 0: compact fragments (private windows -> dense LDS list)
    for (int fb = tid; fb < NF; fb += 512) {
        int o0 = off_d[fb * OPAD + b];
        int o1 = off_d[fb * OPAD + b + 1];
        int len = o1 - o0;
        if (len > 0) {
            int base = atomicAdd(&s_cnt, len);
            for (int k = 0; k < len; ++k) {
                int idx = base + k;
                if (idx < ELC) elist[idx] = pdst[o0 + k];
            }
        }
    }
    __syncthreads();
    int cnt = min(s_cnt, ELC);
    int i4 = tid & 15;
    // phase 1: edge-parallel accumulate, 4-deep (16 edges in flight per wave)
    for (int idx = (tid >> 4); idx < cnt; idx += 128) {
        int j1 = idx + 32, j2 = idx + 64, j3 = idx + 96;
        int e0 = elist[idx];
        int e1 = elist[j1 < cnt ? j1 : idx];
        int e2 = elist[j2 < cnt ? j2 : idx];
        int e3 = elist[j3 < cnt ? j3 : idx];
        int s0 = e0 >> BSH, s1 = e1 >> BSH, s2 = e2 >> BSH, s3 = e3 >> BSH;
        h4v v0 = *(const h4v*)(xh + (long long)s0 * 64 + i4 * 4);
        h4v v1 = *(const h4v*)(xh + (long long)s1 * 64 + i4 * 4);
        h4v v2 = *(const h4v*)(xh + (long long)s2 * 64 + i4 * 4);
        h4v v3 = *(const h4v*)(xh + (long long)s3 * 64 + i4 * 4);
        float w0 = dis[s0], w1 = dis[s1], w2 = dis[s2], w3 = dis[s3];
        float* a0 = &acc[(e0 & (LBS - 1)) * 68 + i4 * 4];
        atomicAdd(&a0[0], w0 * (float)v0[0]);
        atomicAdd(&a0[1], w0 * (float)v0[1]);
        atomicAdd(&a0[2], w0 * (float)v0[2]);
        atomicAdd(&a0[3], w0 * (float)v0[3]);
        if (j1 < cnt) {
            float* a1 = &acc[(e1 & (LBS - 1)) * 68 + i4 * 4];
            atomicAdd(&a1[0], w1 * (float)v1[0]);
            atomicAdd(&a1[1], w1 * (float)v1[1]);
            atomicAdd(&a1[2], w1 * (float)v1[2]);
            atomicAdd(&a1[3], w1 * (float)v1[3]);
        }
        if (j2 < cnt) {
            float* a2 = &acc[(e2 & (LBS - 1)) * 68 + i4 * 4];
            atomicAdd(&a2[0], w2 * (float)v2[0]);
            atomicAdd(&a2[1], w2 * (float)v2[1]);
            atomicAdd(&a2[2], w2 * (float)v2[2]);
            atomicAdd(&a2[3], w2 * (float)v2[3]);
        }
        if (j3 < cnt) {
            float* a3 = &acc[(e3 & (LBS - 1)) * 68 + i4 * 4];
            atomicAdd(&a3[0], w3 * (float)v3[0]);
            atomicAdd(&a3[1], w3 * (float)v3[1]);
            atomicAdd(&a3[2], w3 * (float)v3[2]);
            atomicAdd(&a3[3], w3 * (float)v3[3]);
        }
    }
    __syncthreads();
    // phase 2: finalize + fp16 tile
    for (int idx = tid; idx < LBS * 64; idx += 512) {
        int ln = idx >> 6, f = idx & 63;
        int n = b * LBS + ln;
        unsigned short o = 0;
        if (n < N) {
            float dd = dis[n];
            float xv = h2f_(xh[(long long)n * 64 + f]);
            o = f2h_(dd * (dd * xv + acc[ln * 68 + f]));
        }
        T[ln * 72 + f] = o;
    }
    __syncthreads();
    // phase 3: per-wave dense chain (group rows are wave-private; no barriers)
    int lane = tid & 63, w = tid >> 6;
    int m = lane & 15, q = lane >> 4;
    const unsigned short* arow = &T[(w * 16 + m) * 72 + q * 8];
    hfrag A0 = *(const hfrag*)(arow);
    hfrag A1 = *(const hfrag*)(arow + 32);
    ffrag z[4];
#pragma unroll
    for (int nt = 0; nt < 4; ++nt) {
        hfrag B0 = *(const hfrag*)(Wh1 + (((nt * 2 + 0) * 4 + q) * 16 + m) * 8);
        hfrag B1 = *(const hfrag*)(Wh1 + (((nt * 2 + 1) * 4 + q) * 16 + m) * 8);
        ffrag zz = {0.f, 0.f, 0.f, 0.f};
        zz = __builtin_amdgcn_mfma_f32_16x16x32_f16(A0, B0, zz, 0, 0, 0);
        zz = __builtin_amdgcn_mfma_f32_16x16x32_f16(A1, B1, zz, 0, 0, 0);
        z[nt] = zz;
    }
#pragma unroll
    for (int nt = 0; nt < 4; ++nt) {
        float b1n = Wbuf[4096 + nt * 16 + m];
#pragma unroll
        for (int r = 0; r < 4; ++r) {
            float hv = fmaxf(z[nt][r] + b1n, 0.0f);
            T[(w * 16 + q * 4 + r) * 72 + nt * 16 + m] = f2h_(hv);
        }
    }
    const unsigned short* hrow = &T[(w * 16 + m) * 72 + q * 8];
    hfrag H0 = *(const hfrag*)(hrow);
    hfrag H1 = *(const hfrag*)(hrow + 32);
    hfrag C0 = *(const hfrag*)(Wh2 + ((0 * 4 + q) * 16 + m) * 8);
    hfrag C1 = *(const hfrag*)(Wh2 + ((1 * 4 + q) * 16 + m) * 8);
    ffrag t2 = {0.f, 0.f, 0.f, 0.f};
    t2 = __builtin_amdgcn_mfma_f32_16x16x32_f16(H0, C0, t2, 0, 0, 0);
    t2 = __builtin_amdgcn_mfma_f32_16x16x32_f16(H1, C1, t2, 0, 0, 0);
#pragma unroll
    for (int r = 0; r < 4; ++r) {
        int nn = b * LBS + w * 16 + q * 4 + r;
        if (nn < N) t2b[(size_t)nn * 16 + m] = f2h_(t2[r]);
    }
}

// ---- C4: layer-2 agg per bucket (edge-parallel, LDS accum) + log_softmax ----
__global__ __launch_bounds__(512) void k_l2(const unsigned short* __restrict__ t2b,
                                            const int* __restrict__ flags,
                                            const float* __restrict__ dis,
                                            const int* __restrict__ off_d,
                                            const int* __restrict__ pdst,
                                            const float* __restrict__ Wbuf,
                                            void* __restrict__ out, int N) {
    __shared__ int elist[ELC];
    __shared__ float acc[LBS * 17];          // stride 17: atomic bank-spread
    __shared__ int s_cnt;
    int b = blockIdx.x, tid = threadIdx.x;
    if (tid == 0) s_cnt = 0;
    for (int i = tid; i < LBS * 17; i += 512) acc[i] = 0.f;
    __syncthreads();
    for (int fb = tid; fb < NF; fb += 512) {
        int o0 = off_d[fb * OPAD + b];
        int o1 = off_d[fb * OPAD + b + 1];
        int len = o1 - o0;
        if (len > 0) {
            int base = atomicAdd(&s_cnt, len);
            for (int k = 0; k < len; ++k) {
                int idx = base + k;
                if (idx < ELC) elist[idx] = pdst[o0 + k];
            }
        }
    }
    __syncthreads();
    int cnt = min(s_cnt, ELC);
    int i = tid & 15;
    for (int idx = (tid >> 4); idx < cnt; idx += 64) {
        int j1 = idx + 32;
        int e0 = elist[idx];
        int e1 = elist[j1 < cnt ? j1 : idx];
        int s0 = e0 >> BSH, s1 = e1 >> BSH;
        float v0 = h2f_(t2b[(size_t)s0 * 16 + i]);
        float v1 = h2f_(t2b[(size_t)s1 * 16 + i]);
        float w0 = dis[s0], w1 = dis[s1];
        atomicAdd(&acc[(e0 & (LBS - 1)) * 17 + i], w0 * v0);
        if (j1 < cnt) atomicAdd(&acc[(e1 & (LBS - 1)) * 17 + i], w1 * v1);
    }
    __syncthreads();
    int isF32 = flags[0];
    float b2v = Wbuf[5184 + i];
    for (int ln = (tid >> 4); ln < LBS; ln += 32) {
        int n = b * LBS + ln;
        if (n >= N) continue;
        float dd = dis[n];
        float v = dd * (dd * h2f_(t2b[(size_t)n * 16 + i]) + acc[ln * 17 + i]) + b2v;
        float mx = v;
#pragma unroll
        for (int off = 8; off; off >>= 1) mx = fmaxf(mx, __shfl_xor(mx, off, 16));
        float ex = __expf(v - mx);
        float ss = ex;
#pragma unroll
        for (int off = 8; off; off >>= 1) ss += __shfl_xor(ss, off, 16);
        float r = v - mx - logf(ss);
        size_t oi = (size_t)n * 16 + i;
        if (isF32) ((float*)out)[oi] = r;
        else       ((unsigned short*)out)[oi] = f2b_(r);
    }
}

extern "C" void kernel_launch(void* const* d_in, const int* in_sizes, int n_in,
                              void* d_out, int out_size, void* d_ws, size_t ws_size,
                              hipStream_t stream) {
    const void* x  = d_in[0];
    const int*  ei = (const int*)d_in[1];
    const void* W1 = d_in[2];
    const void* b1 = d_in[3];
    const void* W2 = d_in[4];
    const void* b2 = d_in[5];

    const int N = in_sizes[0] / 64;     // 100000
    const int E = in_sizes[1] / 2;      // 1200000
    const int nbk = (N + LBS - 1) >> BSH;  // 782 buckets of 128 nodes
    const int EPB = (((E + NF - 1) / NF) + 7) & ~7;   // private slice size, 8-aligned

    // 64B-aligned workspace carving (~31 MB)
    char* p = (char*)d_ws;
#define CARVE(ty, name, bytes) ty name = (ty)p; p += (((size_t)(bytes)) + 63) & ~(size_t)63;
    CARVE(int*,   flags,     16)
    CARVE(float*, Wbuf,      5200 * 4)
    CARVE(unsigned short*, Wh1, 4096 * 2)
    CARVE(unsigned short*, Wh2, 1024 * 2)
    CARVE(float*, dis,       (size_t)N * 4)
    CARVE(int*,   off_d,     (size_t)NF * OPAD * 4)
    CARVE(int*,   off_s,     (size_t)NF * OPAD * 4)
    CARVE(int*,   pdst,      (size_t)NF * EPB * 4)
    CARVE(unsigned char*, psrc, (size_t)NF * EPB)
    CARVE(unsigned short*, xh,   (size_t)N * 64 * 2)
    CARVE(unsigned short*, t2b,  (size_t)N * 16 * 2)
#undef CARVE

    k_stage<<<NF + 1 + CONV_BLKS, 256, 0, stream>>>(x, ei, W1, b1, W2, b2,
                                                    E, N, nbk, EPB,
                                                    flags, Wbuf, Wh1, Wh2,
                                                    off_d, off_s, pdst, psrc, xh);
    k_deg<<<nbk, 256, 0, stream>>>(psrc, off_s, dis, N, nbk);
    k_agg<<<nbk, 512, 0, stream>>>(xh, dis, off_d, pdst, Wh1, Wh2, Wbuf, t2b, N);
    k_l2<<<nbk, 512, 0, stream>>>(t2b, flags, dis, off_d, pdst, Wbuf, d_out, N);
}

// Round 13
// 187.542 us; speedup vs baseline: 4.1468x; 4.1468x over previous
//
#include <hip/hip_runtime.h>
#include <hip/hip_bf16.h>

typedef __attribute__((ext_vector_type(8))) _Float16 hfrag;
typedef __attribute__((ext_vector_type(4))) float ffrag;
typedef __attribute__((ext_vector_type(4))) _Float16 h4v;

// bucket = 256 consecutive nodes; supports N <= 131072 (static LDS hist arrays)
#define BSH 8
#define LBS 256
#define CAP_SH 14              // 16384-slot padded psr region per bucket
#define CAP (1 << CAP_SH)
#define NF 512                 // edge partitions; fewer fragments -> cheaper bucket walks
#define OPAD 520               // row stride of the fragment-offset tables (> nbk max 512)
#define CONV_BLKS 384

__device__ __forceinline__ float b2f_(unsigned short u) {
    return __uint_as_float(((unsigned)u) << 16);
}
__device__ __forceinline__ unsigned short f2b_(float v) {
    __hip_bfloat16 h = __float2bfloat16(v);   // RNE
    return *reinterpret_cast<unsigned short*>(&h);
}
__device__ __forceinline__ unsigned short f2h_(float v) {
    _Float16 h = (_Float16)v;                 // RNE
    return __builtin_bit_cast(unsigned short, h);
}
__device__ __forceinline__ float h2f_(unsigned short u) {
    _Float16 h = __builtin_bit_cast(_Float16, u);
    return (float)h;
}

__device__ __forceinline__ float loadF(const void* p, long long i, int isF32) {
    if (isF32) return ((const float*)p)[i];
    return b2f_(((const unsigned short*)p)[i]);
}

__device__ __forceinline__ float4 loadF4(const void* p, long long base, int i4, int isF32) {
    if (isF32) {
        return ((const float4*)((const float*)p + base))[i4];
    } else {
        ushort4 u = ((const ushort4*)((const unsigned short*)p + base))[i4];
        return make_float4(b2f_(u.x), b2f_(u.y), b2f_(u.z), b2f_(u.w));
    }
}

__device__ __forceinline__ void get_edge(const int* ei, int i64, int e, int E, int& s, int& d) {
    if (i64) { s = ei[2 * (long long)e]; d = ei[2 * (long long)E + 2 * (long long)e]; }
    else     { s = ei[e];                d = ei[(long long)E + e]; }
}

// batch-load 4 edges (srcs+dsts) with int4 vector loads; e0 multiple of 4
struct E4 { int s[4]; int d[4]; };
__device__ __forceinline__ E4 load4(const int* __restrict__ ei, int i64, int e0, int E) {
    E4 r;
    if (i64) {
        const int4* ps = (const int4*)(ei + 2 * (long long)e0);
        const int4* pd = (const int4*)(ei + 2 * (long long)E + 2 * (long long)e0);
        int4 a = ps[0], b = ps[1];
        int4 c = pd[0], d = pd[1];
        r.s[0] = a.x; r.s[1] = a.z; r.s[2] = b.x; r.s[3] = b.z;
        r.d[0] = c.x; r.d[1] = c.z; r.d[2] = d.x; r.d[3] = d.z;
    } else {
        int4 a = *(const int4*)(ei + e0);
        int4 c = *(const int4*)(ei + (long long)E + e0);
        r.s[0] = a.x; r.s[1] = a.y; r.s[2] = a.z; r.s[3] = a.w;
        r.d[0] = c.x; r.d[1] = c.y; r.d[2] = c.z; r.d[3] = c.w;
    }
    return r;
}

// exclusive scan of a[0..nEl) in LDS by ONE wave (lane = 0..63), chunked shuffle scan
__device__ __forceinline__ void wave_scan_excl(int* a, int nEl, int lane) {
    int run = 0;
    for (int base = 0; base < nEl; base += 64) {
        int i = base + lane;
        int orig = (i < nEl) ? a[i] : 0;
        int v = orig;
#pragma unroll
        for (int off = 1; off < 64; off <<= 1) {
            int u = __shfl_up(v, off);
            if (lane >= off) v += u;
        }
        if (i < nEl) a[i] = v - orig + run;
        run += __shfl(v, 63);
    }
}

// ---- S1 (single staging kernel, fully independent blocks):
//   blocks [0,NF): local bucket-sort of a PRIVATE contiguous edge slice into a
//     PRIVATE output window (LDS hist -> LDS scan -> local scatter).
//   block NF: dtype detect + flags + weight conversion + fp16 MFMA-fragment pack.
//   blocks > NF: x -> fp16 conversion (locally re-derived dtype flag). ----
__global__ __launch_bounds__(256) void k_stage(const void* __restrict__ x,
                                               const int* __restrict__ ei,
                                               const void* __restrict__ W1, const void* __restrict__ b1,
                                               const void* __restrict__ W2, const void* __restrict__ b2,
                                               int E, int N, int nbk, int EPB,
                                               int* __restrict__ flags, float* __restrict__ Wbuf,
                                               unsigned short* __restrict__ Wh1,
                                               unsigned short* __restrict__ Wh2,
                                               int* __restrict__ off_d, int* __restrict__ off_s,
                                               int* __restrict__ pdst,
                                               unsigned char* __restrict__ psrc,
                                               unsigned short* __restrict__ xh) {
    __shared__ int hd[512], hs[512], cd[512], cs[512];
    __shared__ int s_sane, s_zero;
    int tid = threadIdx.x;
    if (tid == 0) { s_sane = 0; s_zero = 0; }
    __syncthreads();
    const unsigned short* xu = (const unsigned short*)x;
    if (blockIdx.x == NF) {
        int sane = 0;
        for (int k = tid; k < 4096; k += 256) {
            float v = b2f_(xu[2 * k]);
            float a = fabsf(v);
            if (v == 0.0f || (a >= 9.3e-10f && a <= 1.1e9f)) sane++;
        }
        if (sane) atomicAdd(&s_sane, sane);
        int zero = 0;
        for (int k = tid; k < 1024; k += 256) if (ei[2 * k + 1] == 0) zero++;
        if (zero) atomicAdd(&s_zero, zero);
        __syncthreads();
        int f = (s_sane < 3000) ? 1 : 0;   // 1 = f32 input
        if (tid == 0) { flags[0] = f; flags[1] = (s_zero > 512) ? 1 : 0; }
        for (int i = tid; i < 4096; i += 256) Wbuf[i] = loadF(W1, i, f);
        if (tid < 64) Wbuf[4096 + tid] = loadF(b1, tid, f);
        for (int i = tid; i < 1024; i += 256) Wbuf[4160 + i] = loadF(W2, i, f);
        if (tid < 16) Wbuf[5184 + tid] = loadF(b2, tid, f);
        __syncthreads();
        // pack W1/W2 into fp16 MFMA B-fragment order
        for (int i = tid; i < 4096; i += 256) {
            int j = i & 7, m = (i >> 3) & 15, q = (i >> 7) & 3, kn = i >> 9;
            int kt = kn & 1, nt = kn >> 1;
            Wh1[i] = f2h_(Wbuf[(kt * 32 + q * 8 + j) * 64 + nt * 16 + m]);
        }
        for (int i = tid; i < 1024; i += 256) {
            int j = i & 7, m = (i >> 3) & 15, q = (i >> 7) & 3, kt = i >> 9;
            Wh2[i] = f2h_(Wbuf[4160 + (kt * 32 + q * 8 + j) * 16 + m]);
        }
        return;
    }
    if (blockIdx.x > NF) {
        // ---- conv block: local dtype re-derivation (L2-hot), then x->fp16 ----
        int cb = blockIdx.x - NF - 1;
        int sane = 0;
        for (int k = tid; k < 4096; k += 256) {
            float v = b2f_(xu[2 * k]);
            float a = fabsf(v);
            if (v == 0.0f || (a >= 9.3e-10f && a <= 1.1e9f)) sane++;
        }
        if (sane) atomicAdd(&s_sane, sane);
        __syncthreads();
        int f = (s_sane < 3000) ? 1 : 0;
        int n4 = N * 16;   // float4-groups
        int ctid = cb * 256 + tid;
        int stride = CONV_BLKS * 256 * 2;
        for (int i0 = ctid * 2; i0 < n4; i0 += stride) {
            float4 v0 = loadF4(x, 0, i0, f);
            float4 v1 = (i0 + 1 < n4) ? loadF4(x, 0, i0 + 1, f) : make_float4(0, 0, 0, 0);
            ushort4 o0, o1;
            o0.x = f2h_(v0.x); o0.y = f2h_(v0.y); o0.z = f2h_(v0.z); o0.w = f2h_(v0.w);
            o1.x = f2h_(v1.x); o1.y = f2h_(v1.y); o1.z = f2h_(v1.z); o1.w = f2h_(v1.w);
            ((ushort4*)xh)[i0] = o0;
            if (i0 + 1 < n4) ((ushort4*)xh)[i0 + 1] = o1;
        }
        return;
    }
    // ---- edge block fb: private slice [elo, ehi), private window [elo, elo+ecnt) ----
    int zero = 0;
    for (int k = tid; k < 1024; k += 256) if (ei[2 * k + 1] == 0) zero++;
    if (zero) atomicAdd(&s_zero, zero);
    for (int i = tid; i < 512; i += 256) { hd[i] = 0; hs[i] = 0; }
    __syncthreads();
    int i64 = (s_zero > 512) ? 1 : 0;
    int fb = blockIdx.x;
    int elo = fb * EPB;
    int ehi = min(elo + EPB, E);
    if (elo >= E) {    // empty slice: still publish (empty) fragment offsets
        for (int b = tid; b <= nbk; b += 256) {
            off_d[fb * OPAD + b] = E; off_s[fb * OPAD + b] = E;
        }
        return;
    }
    int ecnt = ehi - elo;
    // sweep 1: bucket histogram of the private slice
    for (int e0 = elo + tid * 4; e0 + 4 <= ehi; e0 += 1024) {
        E4 a = load4(ei, i64, e0, E);
#pragma unroll
        for (int u = 0; u < 4; ++u) {
            atomicAdd(&hd[a.d[u] >> BSH], 1);
            atomicAdd(&hs[a.s[u] >> BSH], 1);
        }
    }
    int rem = ecnt & 3, ebase = elo + (ecnt & ~3);
    if (tid < rem) {
        int s, d;
        get_edge(ei, i64, ebase + tid, E, s, d);
        atomicAdd(&hd[d >> BSH], 1);
        atomicAdd(&hs[s >> BSH], 1);
    }
    __syncthreads();
    if (tid < 64)       wave_scan_excl(hd, nbk, tid);
    else if (tid < 128) wave_scan_excl(hs, nbk, tid - 64);
    __syncthreads();
    // publish absolute fragment offsets + init private cursors
    for (int b = tid; b < nbk; b += 256) {
        int od = elo + hd[b], os = elo + hs[b];
        off_d[fb * OPAD + b] = od; cd[b] = od;
        off_s[fb * OPAD + b] = os; cs[b] = os;
    }
    if (tid == 0) { off_d[fb * OPAD + nbk] = elo + ecnt; off_s[fb * OPAD + nbk] = elo + ecnt; }
    __syncthreads();
    // sweep 2: scatter into the PRIVATE window (slice is L1/L2-hot from sweep 1)
    for (int e0 = elo + tid * 4; e0 + 4 <= ehi; e0 += 1024) {
        E4 a = load4(ei, i64, e0, E);
#pragma unroll
        for (int u = 0; u < 4; ++u) {
            int p = atomicAdd(&cd[a.d[u] >> BSH], 1);
            pdst[p] = (a.s[u] << BSH) | (a.d[u] & (LBS - 1));
            int q = atomicAdd(&cs[a.s[u] >> BSH], 1);
            psrc[q] = (unsigned char)(a.s[u] & (LBS - 1));
        }
    }
    if (tid < rem) {
        int s, d;
        get_edge(ei, i64, ebase + tid, E, s, d);
        int p = atomicAdd(&cd[d >> BSH], 1);
        pdst[p] = (s << BSH) | (d & (LBS - 1));
        int q = atomicAdd(&cs[s >> BSH], 1);
        psrc[q] = (unsigned char)(s & (LBS - 1));
    }
}

// ---- C2 (fused deg + csr, one block per bucket, 512 threads):
//   phase 1: src-degree hist from psrc fragments -> dis = rsqrt(deg+1)
//   phase 2: dst CSR from pdst fragments -> row_se + psr (src index only) ----
__global__ __launch_bounds__(512) void k_degcsr(const unsigned char* __restrict__ psrc,
                                                const int* __restrict__ pdst,
                                                const int* __restrict__ off_s,
                                                const int* __restrict__ off_d,
                                                float* __restrict__ dis,
                                                int2* __restrict__ row_se,
                                                int* __restrict__ psr, int N, int nbk) {
    __shared__ int h[LBS], lb[LBS], cur[LBS];
    int b = blockIdx.x, tid = threadIdx.x;
    if (tid < LBS) h[tid] = 0;
    __syncthreads();
    for (int fb = tid; fb < NF; fb += 512) {
        int o0 = off_s[fb * OPAD + b];
        int o1 = off_s[fb * OPAD + b + 1];
        for (int p = o0; p < o1; ++p) atomicAdd(&h[psrc[p]], 1);
    }
    __syncthreads();
    if (tid < LBS) {
        int node = b * LBS + tid;
        if (node < N) dis[node] = rsqrtf((float)h[tid] + 1.0f);
    }
    __syncthreads();
    if (tid < LBS) h[tid] = 0;
    __syncthreads();
    for (int fb = tid; fb < NF; fb += 512) {
        int o0 = off_d[fb * OPAD + b];
        int o1 = off_d[fb * OPAD + b + 1];
        for (int p = o0; p < o1; ++p) atomicAdd(&h[pdst[p] & (LBS - 1)], 1);
    }
    __syncthreads();
    if (tid < LBS) lb[tid] = h[tid];
    __syncthreads();
    if (tid < 64) wave_scan_excl(lb, LBS, tid);
    __syncthreads();
    int beg = b << CAP_SH;
    if (tid < LBS) {
        cur[tid] = lb[tid];
        int node = b * LBS + tid;
        if (node < N) {
            int s0 = min(lb[tid], CAP), s1 = min(lb[tid] + h[tid], CAP);
            row_se[node] = make_int2(beg + s0, beg + s1);
        }
    }
    __syncthreads();
    for (int fb = tid; fb < NF; fb += 512) {
        int o0 = off_d[fb * OPAD + b];
        int o1 = off_d[fb * OPAD + b + 1];
        for (int p = o0; p < o1; ++p) {
            int e = pdst[p];
            int r = atomicAdd(&cur[e & (LBS - 1)], 1);
            if (r < CAP) psr[beg + r] = e >> BSH;
        }
    }
}

// ---- fused aggregation + dense chain (16-node block = 4 waves x 4 nodes):
//   phase A: AGG via 8-deep gather pipeline (psr src + L2 dis) -> fp16 LDS tile
//   phase B: layer1 MFMA -> relu+bias -> H in LDS (reused)
//   phase C: layer2 MFMA (wave 0) -> t2b ----
__global__ __launch_bounds__(256) void k_aggdense(const unsigned short* __restrict__ xh,
                                                  const float* __restrict__ dis,
                                                  const int2* __restrict__ row_se,
                                                  const int* __restrict__ psr,
                                                  const unsigned short* __restrict__ Wh1,
                                                  const unsigned short* __restrict__ Wh2,
                                                  const float* __restrict__ Wbuf,
                                                  unsigned short* __restrict__ t2b, int N) {
    __shared__ __align__(16) unsigned short T[16 * 72];
    int tid = threadIdx.x;
    int lane = tid & 63;
    int w = tid >> 6;
    int g = lane >> 4, i4 = lane & 15;
    int ln = w * 4 + g;                      // local node 0..15
    int n = blockIdx.x * 16 + ln;
    int act = (n < N);
    float4 A[4];
#pragma unroll
    for (int u = 0; u < 4; ++u) A[u] = make_float4(0.f, 0.f, 0.f, 0.f);
    float dd = 0.f;
    int beg = 0, end = 0;
    if (act) {
        dd = dis[n];
        int2 se = row_se[n];
        beg = se.x; end = se.y;
        h4v xv = *(const h4v*)(xh + (long long)n * 64 + i4 * 4);
        float ww = dd * dd;
        A[0].x = ww * (float)xv[0]; A[0].y = ww * (float)xv[1];
        A[0].z = ww * (float)xv[2]; A[0].w = ww * (float)xv[3];
    }
    int cnt = end - beg;
    int Tn = (cnt + 7) >> 3;
    int p = beg;
    int e[8];
#pragma unroll
    for (int u = 0; u < 8; ++u) e[u] = psr[p + u];
    for (int t = 0; t < Tn; ++t) {
        h4v hv[8];
        float dv[8];
#pragma unroll
        for (int u = 0; u < 8; ++u) {
            unsigned ex = min((unsigned)e[u], (unsigned)(N - 1));
            hv[u] = *(const h4v*)(xh + (long long)ex * 64 + i4 * 4);
            dv[u] = dis[ex];
        }
        float nv[8];
#pragma unroll
        for (int u = 0; u < 8; ++u) nv[u] = (p + u < end) ? dd * dv[u] : 0.f;
#pragma unroll
        for (int u = 0; u < 8; ++u) e[u] = psr[p + 8 + u];
        p += 8;
#pragma unroll
        for (int u = 0; u < 8; ++u) {
            A[u & 3].x += nv[u] * (float)hv[u][0];
            A[u & 3].y += nv[u] * (float)hv[u][1];
            A[u & 3].z += nv[u] * (float)hv[u][2];
            A[u & 3].w += nv[u] * (float)hv[u][3];
        }
    }
    float4 s;
    s.x = A[0].x + A[1].x + A[2].x + A[3].x;
    s.y = A[0].y + A[1].y + A[2].y + A[3].y;
    s.z = A[0].z + A[1].z + A[2].z + A[3].z;
    s.w = A[0].w + A[1].w + A[2].w + A[3].w;
    ushort4 o;
    o.x = f2h_(s.x); o.y = f2h_(s.y); o.z = f2h_(s.z); o.w = f2h_(s.w);
    *(ushort4*)(&T[ln * 72 + i4 * 4]) = o;       // T[node][feat], stride 72
    __syncthreads();
    // ---- phase B: layer 1, wave w handles N-tile nt = w ----
    int m = lane & 15, q = lane >> 4;
    const unsigned short* arow = &T[m * 72 + q * 8];
    hfrag A0 = *(const hfrag*)(arow);
    hfrag A1 = *(const hfrag*)(arow + 32);
    int nt = w;
    hfrag B0 = *(const hfrag*)(Wh1 + (((nt * 2 + 0) * 4 + q) * 16 + m) * 8);
    hfrag B1 = *(const hfrag*)(Wh1 + (((nt * 2 + 1) * 4 + q) * 16 + m) * 8);
    ffrag z = {0.f, 0.f, 0.f, 0.f};
    z = __builtin_amdgcn_mfma_f32_16x16x32_f16(A0, B0, z, 0, 0, 0);
    z = __builtin_amdgcn_mfma_f32_16x16x32_f16(A1, B1, z, 0, 0, 0);
    float b1n = Wbuf[4096 + nt * 16 + m];
    __syncthreads();                              // all A-frag reads of T done
#pragma unroll
    for (int r = 0; r < 4; ++r) {
        float hv = fmaxf(z[r] + b1n, 0.0f);
        T[(q * 4 + r) * 72 + nt * 16 + m] = f2h_(hv);
    }
    __syncthreads();
    // ---- phase C: layer 2 on wave 0 ----
    if (w == 0) {
        const unsigned short* hrow = &T[m * 72 + q * 8];
        hfrag H0 = *(const hfrag*)(hrow);
        hfrag H1 = *(const hfrag*)(hrow + 32);
        hfrag C0 = *(const hfrag*)(Wh2 + ((0 * 4 + q) * 16 + m) * 8);
        hfrag C1 = *(const hfrag*)(Wh2 + ((1 * 4 + q) * 16 + m) * 8);
        ffrag t2 = {0.f, 0.f, 0.f, 0.f};
        t2 = __builtin_amdgcn_mfma_f32_16x16x32_f16(H0, C0, t2, 0, 0, 0);
        t2 = __builtin_amdgcn_mfma_f32_16x16x32_f16(H1, C1, t2, 0, 0, 0);
#pragma unroll
        for (int r = 0; r < 4; ++r) {
            int nn = blockIdx.x * 16 + q * 4 + r;
            if (nn < N) t2b[(size_t)nn * 16 + m] = f2h_(t2[r]);
        }
    }
}

// ---- layer 2: gather T2 (fp16) + b2 + log_softmax -> out (8-deep pipeline) ----
__global__ __launch_bounds__(256) void k_l2(const unsigned short* __restrict__ t2b,
                                            const int* __restrict__ flags,
                                            const float* __restrict__ dis,
                                            const int2* __restrict__ row_se,
                                            const int* __restrict__ psr,
                                            const float* __restrict__ Wbuf,
                                            void* __restrict__ out, int N) {
    int isF32 = flags[0];
    int tid = threadIdx.x, lane = tid & 63;
    int g = lane >> 4, i = lane & 15;
    int n = blockIdx.x * 16 + (tid >> 6) * 4 + g;
    if (n >= N) return;
    float dd = dis[n];
    int2 se = row_se[n];
    int beg = se.x, end = se.y;
    int cnt = end - beg;
    float A[4];
    A[0] = dd * dd * h2f_(t2b[(size_t)n * 16 + i]);
    A[1] = 0.f; A[2] = 0.f; A[3] = 0.f;
    int T = (cnt + 7) >> 3;
    int p = beg;
    int e[8];
#pragma unroll
    for (int u = 0; u < 8; ++u) e[u] = psr[p + u];
    for (int t = 0; t < T; ++t) {
        float r[8], dv[8];
#pragma unroll
        for (int u = 0; u < 8; ++u) {
            unsigned ex = min((unsigned)e[u], (unsigned)(N - 1));
            r[u] = h2f_(t2b[(size_t)ex * 16 + i]);
            dv[u] = dis[ex];
        }
        float nv[8];
#pragma unroll
        for (int u = 0; u < 8; ++u) nv[u] = (p + u < end) ? dd * dv[u] : 0.f;
#pragma unroll
        for (int u = 0; u < 8; ++u) e[u] = psr[p + 8 + u];
        p += 8;
#pragma unroll
        for (int u = 0; u < 8; ++u) A[u & 3] += nv[u] * r[u];
    }
    float a0 = A[0] + A[1] + A[2] + A[3];
    float v = a0 + Wbuf[5184 + i];
    float mx = v;
#pragma unroll
    for (int off = 8; off; off >>= 1) mx = fmaxf(mx, __shfl_xor(mx, off, 16));
    float ex = __expf(v - mx);
    float ss = ex;
#pragma unroll
    for (int off = 8; off; off >>= 1) ss += __shfl_xor(ss, off, 16);
    float r = v - mx - logf(ss);
    size_t oi = (size_t)n * 16 + i;
    if (isF32) ((float*)out)[oi] = r;
    else       ((unsigned short*)out)[oi] = f2b_(r);
}

extern "C" void kernel_launch(void* const* d_in, const int* in_sizes, int n_in,
                              void* d_out, int out_size, void* d_ws, size_t ws_size,
                              hipStream_t stream) {
    const void* x  = d_in[0];
    const int*  ei = (const int*)d_in[1];
    const void* W1 = d_in[2];
    const void* b1 = d_in[3];
    const void* W2 = d_in[4];
    const void* b2 = d_in[5];

    const int N = in_sizes[0] / 64;     // 100000
    const int E = in_sizes[1] / 2;      // 1200000
    const int nbk = (N + LBS - 1) >> BSH;  // 391 coarse buckets
    const int EPB = (((E + NF - 1) / NF) + 7) & ~7;   // private slice size, 8-aligned

    // 64B-aligned workspace carving (~65 MB)
    char* p = (char*)d_ws;
#define CARVE(ty, name, bytes) ty name = (ty)p; p += (((size_t)(bytes)) + 63) & ~(size_t)63;
    CARVE(int*,   flags,     16)
    CARVE(float*, Wbuf,      5200 * 4)
    CARVE(unsigned short*, Wh1, 4096 * 2)
    CARVE(unsigned short*, Wh2, 1024 * 2)
    CARVE(float*, dis,       (size_t)N * 4)
    CARVE(int2*,  row_se,    (size_t)N * 8)
    CARVE(int*,   off_d,     (size_t)NF * OPAD * 4)
    CARVE(int*,   off_s,     (size_t)NF * OPAD * 4)
    CARVE(int*,   pdst,      (size_t)NF * EPB * 4)
    CARVE(unsigned char*, psrc, (size_t)NF * EPB)
    CARVE(int*,   psr,       (((size_t)nbk << CAP_SH) + 64) * 4)
    CARVE(unsigned short*, xh,   (size_t)N * 64 * 2)
    CARVE(unsigned short*, t2b,  (size_t)N * 16 * 2)
#undef CARVE

    k_stage<<<NF + 1 + CONV_BLKS, 256, 0, stream>>>(x, ei, W1, b1, W2, b2,
                                                    E, N, nbk, EPB,
                                                    flags, Wbuf, Wh1, Wh2,
                                                    off_d, off_s, pdst, psrc, xh);
    k_degcsr<<<nbk, 512, 0, stream>>>(psrc, pdst, off_s, off_d, dis, row_se, psr, N, nbk);
    k_aggdense<<<(N + 15) / 16, 256, 0, stream>>>(xh, dis, row_se, psr,
                                                  Wh1, Wh2, Wbuf, t2b, N);
    k_l2<<<(N + 15) / 16, 256, 0, stream>>>(t2b, flags, dis, row_se, psr, Wbuf, d_out, N);
}

// Round 14
// 180.841 us; speedup vs baseline: 4.3005x; 1.0371x over previous
//
#include <hip/hip_runtime.h>
#include <hip/hip_bf16.h>

typedef __attribute__((ext_vector_type(8))) _Float16 hfrag;
typedef __attribute__((ext_vector_type(4))) float ffrag;
typedef __attribute__((ext_vector_type(4))) _Float16 h4v;

// bucket = 256 consecutive nodes; supports N <= 131072 (static LDS hist arrays)
#define BSH 8
#define LBS 256
#define CAP_SH 14              // 16384-slot padded psr region per bucket
#define CAP (1 << CAP_SH)
#define NF 512                 // edge partitions
#define OPAD 520               // row stride of the fragment-offset tables (> nbk max 512)
#define CONV_BLKS 384
#define EPBC 4096              // LDS edge-staging capacity in k_stage
#define ELC 4096               // LDS bucket-edge capacity in k_degcsr (mean 3070)

__device__ __forceinline__ float b2f_(unsigned short u) {
    return __uint_as_float(((unsigned)u) << 16);
}
__device__ __forceinline__ unsigned short f2b_(float v) {
    __hip_bfloat16 h = __float2bfloat16(v);   // RNE
    return *reinterpret_cast<unsigned short*>(&h);
}
__device__ __forceinline__ unsigned short f2h_(float v) {
    _Float16 h = (_Float16)v;                 // RNE
    return __builtin_bit_cast(unsigned short, h);
}
__device__ __forceinline__ float h2f_(unsigned short u) {
    _Float16 h = __builtin_bit_cast(_Float16, u);
    return (float)h;
}

__device__ __forceinline__ float loadF(const void* p, long long i, int isF32) {
    if (isF32) return ((const float*)p)[i];
    return b2f_(((const unsigned short*)p)[i]);
}

__device__ __forceinline__ float4 loadF4(const void* p, long long base, int i4, int isF32) {
    if (isF32) {
        return ((const float4*)((const float*)p + base))[i4];
    } else {
        ushort4 u = ((const ushort4*)((const unsigned short*)p + base))[i4];
        return make_float4(b2f_(u.x), b2f_(u.y), b2f_(u.z), b2f_(u.w));
    }
}

__device__ __forceinline__ void get_edge(const int* ei, int i64, int e, int E, int& s, int& d) {
    if (i64) { s = ei[2 * (long long)e]; d = ei[2 * (long long)E + 2 * (long long)e]; }
    else     { s = ei[e];                d = ei[(long long)E + e]; }
}

// batch-load 4 edges (srcs+dsts) with int4 vector loads; e0 multiple of 4
struct E4 { int s[4]; int d[4]; };
__device__ __forceinline__ E4 load4(const int* __restrict__ ei, int i64, int e0, int E) {
    E4 r;
    if (i64) {
        const int4* ps = (const int4*)(ei + 2 * (long long)e0);
        const int4* pd = (const int4*)(ei + 2 * (long long)E + 2 * (long long)e0);
        int4 a = ps[0], b = ps[1];
        int4 c = pd[0], d = pd[1];
        r.s[0] = a.x; r.s[1] = a.z; r.s[2] = b.x; r.s[3] = b.z;
        r.d[0] = c.x; r.d[1] = c.z; r.d[2] = d.x; r.d[3] = d.z;
    } else {
        int4 a = *(const int4*)(ei + e0);
        int4 c = *(const int4*)(ei + (long long)E + e0);
        r.s[0] = a.x; r.s[1] = a.y; r.s[2] = a.z; r.s[3] = a.w;
        r.d[0] = c.x; r.d[1] = c.y; r.d[2] = c.z; r.d[3] = c.w;
    }
    return r;
}

// exclusive scan of a[0..nEl) in LDS by ONE wave (lane = 0..63), chunked shuffle scan
__device__ __forceinline__ void wave_scan_excl(int* a, int nEl, int lane) {
    int run = 0;
    for (int base = 0; base < nEl; base += 64) {
        int i = base + lane;
        int orig = (i < nEl) ? a[i] : 0;
        int v = orig;
#pragma unroll
        for (int off = 1; off < 64; off <<= 1) {
            int u = __shfl_up(v, off);
            if (lane >= off) v += u;
        }
        if (i < nEl) a[i] = v - orig + run;
        run += __shfl(v, 63);
    }
}

// ---- S1 (single staging kernel, fully independent blocks):
//   blocks [0,NF): ONE global sweep — slice staged in LDS, then hist/scan/scatter
//     from LDS into a PRIVATE output window.
//   block NF: dtype detect + flags + weight conversion + fp16 MFMA-fragment pack.
//   blocks > NF: x -> fp16 conversion (locally re-derived dtype flag). ----
__global__ __launch_bounds__(256) void k_stage(const void* __restrict__ x,
                                               const int* __restrict__ ei,
                                               const void* __restrict__ W1, const void* __restrict__ b1,
                                               const void* __restrict__ W2, const void* __restrict__ b2,
                                               int E, int N, int nbk, int EPB,
                                               int* __restrict__ flags, float* __restrict__ Wbuf,
                                               unsigned short* __restrict__ Wh1,
                                               unsigned short* __restrict__ Wh2,
                                               int* __restrict__ off_d, int* __restrict__ off_s,
                                               int* __restrict__ pdst,
                                               unsigned char* __restrict__ psrc,
                                               unsigned short* __restrict__ xh) {
    __shared__ int hd[512], hs[512], cd[512], cs[512];
    __shared__ int es[EPBC], ed[EPBC];   // LDS edge staging (32 KB)
    __shared__ int s_sane, s_zero;
    int tid = threadIdx.x;
    if (tid == 0) { s_sane = 0; s_zero = 0; }
    __syncthreads();
    const unsigned short* xu = (const unsigned short*)x;
    if (blockIdx.x == NF) {
        int sane = 0;
        for (int k = tid; k < 4096; k += 256) {
            float v = b2f_(xu[2 * k]);
            float a = fabsf(v);
            if (v == 0.0f || (a >= 9.3e-10f && a <= 1.1e9f)) sane++;
        }
        if (sane) atomicAdd(&s_sane, sane);
        int zero = 0;
        for (int k = tid; k < 1024; k += 256) if (ei[2 * k + 1] == 0) zero++;
        if (zero) atomicAdd(&s_zero, zero);
        __syncthreads();
        int f = (s_sane < 3000) ? 1 : 0;   // 1 = f32 input
        if (tid == 0) { flags[0] = f; flags[1] = (s_zero > 512) ? 1 : 0; }
        for (int i = tid; i < 4096; i += 256) Wbuf[i] = loadF(W1, i, f);
        if (tid < 64) Wbuf[4096 + tid] = loadF(b1, tid, f);
        for (int i = tid; i < 1024; i += 256) Wbuf[4160 + i] = loadF(W2, i, f);
        if (tid < 16) Wbuf[5184 + tid] = loadF(b2, tid, f);
        __syncthreads();
        // pack W1/W2 into fp16 MFMA B-fragment order
        for (int i = tid; i < 4096; i += 256) {
            int j = i & 7, m = (i >> 3) & 15, q = (i >> 7) & 3, kn = i >> 9;
            int kt = kn & 1, nt = kn >> 1;
            Wh1[i] = f2h_(Wbuf[(kt * 32 + q * 8 + j) * 64 + nt * 16 + m]);
        }
        for (int i = tid; i < 1024; i += 256) {
            int j = i & 7, m = (i >> 3) & 15, q = (i >> 7) & 3, kt = i >> 9;
            Wh2[i] = f2h_(Wbuf[4160 + (kt * 32 + q * 8 + j) * 16 + m]);
        }
        return;
    }
    if (blockIdx.x > NF) {
        // ---- conv block: local dtype re-derivation (L2-hot), then x->fp16 ----
        int cb = blockIdx.x - NF - 1;
        int sane = 0;
        for (int k = tid; k < 4096; k += 256) {
            float v = b2f_(xu[2 * k]);
            float a = fabsf(v);
            if (v == 0.0f || (a >= 9.3e-10f && a <= 1.1e9f)) sane++;
        }
        if (sane) atomicAdd(&s_sane, sane);
        __syncthreads();
        int f = (s_sane < 3000) ? 1 : 0;
        int n4 = N * 16;   // float4-groups
        int ctid = cb * 256 + tid;
        int stride = CONV_BLKS * 256 * 2;
        for (int i0 = ctid * 2; i0 < n4; i0 += stride) {
            float4 v0 = loadF4(x, 0, i0, f);
            float4 v1 = (i0 + 1 < n4) ? loadF4(x, 0, i0 + 1, f) : make_float4(0, 0, 0, 0);
            ushort4 o0, o1;
            o0.x = f2h_(v0.x); o0.y = f2h_(v0.y); o0.z = f2h_(v0.z); o0.w = f2h_(v0.w);
            o1.x = f2h_(v1.x); o1.y = f2h_(v1.y); o1.z = f2h_(v1.z); o1.w = f2h_(v1.w);
            ((ushort4*)xh)[i0] = o0;
            if (i0 + 1 < n4) ((ushort4*)xh)[i0 + 1] = o1;
        }
        return;
    }
    // ---- edge block fb: private slice [elo, ehi), private window [elo, elo+ecnt) ----
    int zero = 0;
    for (int k = tid; k < 1024; k += 256) if (ei[2 * k + 1] == 0) zero++;
    if (zero) atomicAdd(&s_zero, zero);
    for (int i = tid; i < 512; i += 256) { hd[i] = 0; hs[i] = 0; }
    __syncthreads();
    int i64 = (s_zero > 512) ? 1 : 0;
    int fb = blockIdx.x;
    int elo = fb * EPB;
    int ehi = min(elo + EPB, E);
    if (elo >= E) {    // empty slice: still publish (empty) fragment offsets
        for (int b = tid; b <= nbk; b += 256) {
            off_d[fb * OPAD + b] = E; off_s[fb * OPAD + b] = E;
        }
        return;
    }
    int ecnt = ehi - elo;
    int rem = ecnt & 3, ebase = elo + (ecnt & ~3);
    if (ecnt <= EPBC) {
        // ---- single global sweep: stage slice in LDS ----
        for (int e0 = elo + tid * 4; e0 + 4 <= ehi; e0 += 1024) {
            E4 a = load4(ei, i64, e0, E);
            int base = e0 - elo;
#pragma unroll
            for (int u = 0; u < 4; ++u) { es[base + u] = a.s[u]; ed[base + u] = a.d[u]; }
        }
        if (tid < rem) {
            int s, d;
            get_edge(ei, i64, ebase + tid, E, s, d);
            es[ecnt - rem + tid] = s; ed[ecnt - rem + tid] = d;
        }
        __syncthreads();
        // hist from LDS
        for (int i = tid; i < ecnt; i += 256) {
            atomicAdd(&hd[ed[i] >> BSH], 1);
            atomicAdd(&hs[es[i] >> BSH], 1);
        }
        __syncthreads();
        if (tid < 64)       wave_scan_excl(hd, nbk, tid);
        else if (tid < 128) wave_scan_excl(hs, nbk, tid - 64);
        __syncthreads();
        for (int b = tid; b < nbk; b += 256) {
            int od = elo + hd[b], os = elo + hs[b];
            off_d[fb * OPAD + b] = od; cd[b] = od;
            off_s[fb * OPAD + b] = os; cs[b] = os;
        }
        if (tid == 0) { off_d[fb * OPAD + nbk] = elo + ecnt; off_s[fb * OPAD + nbk] = elo + ecnt; }
        __syncthreads();
        // scatter from LDS
        for (int i = tid; i < ecnt; i += 256) {
            int s = es[i], d = ed[i];
            int p = atomicAdd(&cd[d >> BSH], 1);
            pdst[p] = (s << BSH) | (d & (LBS - 1));
            int q = atomicAdd(&cs[s >> BSH], 1);
            psrc[q] = (unsigned char)(s & (LBS - 1));
        }
        return;
    }
    // ---- fallback: two global sweeps (slice too large for LDS) ----
    for (int e0 = elo + tid * 4; e0 + 4 <= ehi; e0 += 1024) {
        E4 a = load4(ei, i64, e0, E);
#pragma unroll
        for (int u = 0; u < 4; ++u) {
            atomicAdd(&hd[a.d[u] >> BSH], 1);
            atomicAdd(&hs[a.s[u] >> BSH], 1);
        }
    }
    if (tid < rem) {
        int s, d;
        get_edge(ei, i64, ebase + tid, E, s, d);
        atomicAdd(&hd[d >> BSH], 1);
        atomicAdd(&hs[s >> BSH], 1);
    }
    __syncthreads();
    if (tid < 64)       wave_scan_excl(hd, nbk, tid);
    else if (tid < 128) wave_scan_excl(hs, nbk, tid - 64);
    __syncthreads();
    for (int b = tid; b < nbk; b += 256) {
        int od = elo + hd[b], os = elo + hs[b];
        off_d[fb * OPAD + b] = od; cd[b] = od;
        off_s[fb * OPAD + b] = os; cs[b] = os;
    }
    if (tid == 0) { off_d[fb * OPAD + nbk] = elo + ecnt; off_s[fb * OPAD + nbk] = elo + ecnt; }
    __syncthreads();
    for (int e0 = elo + tid * 4; e0 + 4 <= ehi; e0 += 1024) {
        E4 a = load4(ei, i64, e0, E);
#pragma unroll
        for (int u = 0; u < 4; ++u) {
            int p = atomicAdd(&cd[a.d[u] >> BSH], 1);
            pdst[p] = (a.s[u] << BSH) | (a.d[u] & (LBS - 1));
            int q = atomicAdd(&cs[a.s[u] >> BSH], 1);
            psrc[q] = (unsigned char)(a.s[u] & (LBS - 1));
        }
    }
    if (tid < rem) {
        int s, d;
        get_edge(ei, i64, ebase + tid, E, s, d);
        int p = atomicAdd(&cd[d >> BSH], 1);
        pdst[p] = (s << BSH) | (d & (LBS - 1));
        int q = atomicAdd(&cs[s >> BSH], 1);
        psrc[q] = (unsigned char)(s & (LBS - 1));
    }
}

// ---- C2 (fused deg + csr, one block per bucket, 512 threads):
//   phase 1: src-degree hist from psrc fragments -> dis = rsqrt(deg+1)
//   phase 2: compact dst fragments into LDS (ONE walk + ONE pdst pass), then
//            hist/scan/scatter from LDS -> row_se + psr. Fallback if overflow. ----
__global__ __launch_bounds__(512) void k_degcsr(const unsigned char* __restrict__ psrc,
                                                const int* __restrict__ pdst,
                                                const int* __restrict__ off_s,
                                                const int* __restrict__ off_d,
                                                float* __restrict__ dis,
                                                int2* __restrict__ row_se,
                                                int* __restrict__ psr, int N, int nbk) {
    __shared__ int elist[ELC];           // 16 KB
    __shared__ int h[LBS], lb[LBS], cur[LBS];
    __shared__ int s_cnt;
    int b = blockIdx.x, tid = threadIdx.x;
    if (tid == 0) s_cnt = 0;
    if (tid < LBS) h[tid] = 0;
    __syncthreads();
    // phase 1: src-degree hist (single fragment walk)
    for (int fb = tid; fb < NF; fb += 512) {
        int o0 = off_s[fb * OPAD + b];
        int o1 = off_s[fb * OPAD + b + 1];
        for (int p = o0; p < o1; ++p) atomicAdd(&h[psrc[p]], 1);
    }
    __syncthreads();
    if (tid < LBS) {
        int node = b * LBS + tid;
        if (node < N) dis[node] = rsqrtf((float)h[tid] + 1.0f);
    }
    __syncthreads();
    if (tid < LBS) h[tid] = 0;
    __syncthreads();
    // phase 2a: compact dst fragments into LDS (the ONLY off_d walk)
    for (int fb = tid; fb < NF; fb += 512) {
        int o0 = off_d[fb * OPAD + b];
        int o1 = off_d[fb * OPAD + b + 1];
        int len = o1 - o0;
        if (len > 0) {
            int base = atomicAdd(&s_cnt, len);
            for (int k = 0; k < len; ++k)
                if (base + k < ELC) elist[base + k] = pdst[o0 + k];
        }
    }
    __syncthreads();
    int cnt = s_cnt;
    int beg = b << CAP_SH;
    if (cnt <= ELC) {
        // phase 2b: hist + scan + scatter entirely from LDS
        for (int i = tid; i < cnt; i += 512) atomicAdd(&h[elist[i] & (LBS - 1)], 1);
        __syncthreads();
        if (tid < LBS) lb[tid] = h[tid];
        __syncthreads();
        if (tid < 64) wave_scan_excl(lb, LBS, tid);
        __syncthreads();
        if (tid < LBS) {
            cur[tid] = lb[tid];
            int node = b * LBS + tid;
            if (node < N) {
                int s0 = min(lb[tid], CAP), s1 = min(lb[tid] + h[tid], CAP);
                row_se[node] = make_int2(beg + s0, beg + s1);
            }
        }
        __syncthreads();
        for (int i = tid; i < cnt; i += 512) {
            int e = elist[i];
            int r = atomicAdd(&cur[e & (LBS - 1)], 1);
            if (r < CAP) psr[beg + r] = e >> BSH;
        }
        return;
    }
    // ---- fallback: 2-pass global walks (bucket overflow) ----
    if (tid < LBS) h[tid] = 0;
    __syncthreads();
    for (int fb = tid; fb < NF; fb += 512) {
        int o0 = off_d[fb * OPAD + b];
        int o1 = off_d[fb * OPAD + b + 1];
        for (int p = o0; p < o1; ++p) atomicAdd(&h[pdst[p] & (LBS - 1)], 1);
    }
    __syncthreads();
    if (tid < LBS) lb[tid] = h[tid];
    __syncthreads();
    if (tid < 64) wave_scan_excl(lb, LBS, tid);
    __syncthreads();
    if (tid < LBS) {
        cur[tid] = lb[tid];
        int node = b * LBS + tid;
        if (node < N) {
            int s0 = min(lb[tid], CAP), s1 = min(lb[tid] + h[tid], CAP);
            row_se[node] = make_int2(beg + s0, beg + s1);
        }
    }
    __syncthreads();
    for (int fb = tid; fb < NF; fb += 512) {
        int o0 = off_d[fb * OPAD + b];
        int o1 = off_d[fb * OPAD + b + 1];
        for (int p = o0; p < o1; ++p) {
            int e = pdst[p];
            int r = atomicAdd(&cur[e & (LBS - 1)], 1);
            if (r < CAP) psr[beg + r] = e >> BSH;
        }
    }
}

// ---- fused aggregation + dense chain (16-node block = 4 waves x 4 nodes):
//   phase A: AGG via 8-deep gather pipeline (psr src + L2 dis) -> fp16 LDS tile
//   phase B: layer1 MFMA -> relu+bias -> H in LDS (reused)
//   phase C: layer2 MFMA (wave 0) -> t2b ----
__global__ __launch_bounds__(256) void k_aggdense(const unsigned short* __restrict__ xh,
                                                  const float* __restrict__ dis,
                                                  const int2* __restrict__ row_se,
                                                  const int* __restrict__ psr,
                                                  const unsigned short* __restrict__ Wh1,
                                                  const unsigned short* __restrict__ Wh2,
                                                  const float* __restrict__ Wbuf,
                                                  unsigned short* __restrict__ t2b, int N) {
    __shared__ __align__(16) unsigned short T[16 * 72];
    int tid = threadIdx.x;
    int lane = tid & 63;
    int w = tid >> 6;
    int g = lane >> 4, i4 = lane & 15;
    int ln = w * 4 + g;                      // local node 0..15
    int n = blockIdx.x * 16 + ln;
    int act = (n < N);
    float4 A[4];
#pragma unroll
    for (int u = 0; u < 4; ++u) A[u] = make_float4(0.f, 0.f, 0.f, 0.f);
    float dd = 0.f;
    int beg = 0, end = 0;
    if (act) {
        dd = dis[n];
        int2 se = row_se[n];
        beg = se.x; end = se.y;
        h4v xv = *(const h4v*)(xh + (long long)n * 64 + i4 * 4);
        float ww = dd * dd;
        A[0].x = ww * (float)xv[0]; A[0].y = ww * (float)xv[1];
        A[0].z = ww * (float)xv[2]; A[0].w = ww * (float)xv[3];
    }
    int cnt = end - beg;
    int Tn = (cnt + 7) >> 3;
    int p = beg;
    int e[8];
#pragma unroll
    for (int u = 0; u < 8; ++u) e[u] = psr[p + u];
    for (int t = 0; t < Tn; ++t) {
        h4v hv[8];
        float dv[8];
#pragma unroll
        for (int u = 0; u < 8; ++u) {
            unsigned ex = min((unsigned)e[u], (unsigned)(N - 1));
            hv[u] = *(const h4v*)(xh + (long long)ex * 64 + i4 * 4);
            dv[u] = dis[ex];
        }
        float nv[8];
#pragma unroll
        for (int u = 0; u < 8; ++u) nv[u] = (p + u < end) ? dd * dv[u] : 0.f;
#pragma unroll
        for (int u = 0; u < 8; ++u) e[u] = psr[p + 8 + u];
        p += 8;
#pragma unroll
        for (int u = 0; u < 8; ++u) {
            A[u & 3].x += nv[u] * (float)hv[u][0];
            A[u & 3].y += nv[u] * (float)hv[u][1];
            A[u & 3].z += nv[u] * (float)hv[u][2];
            A[u & 3].w += nv[u] * (float)hv[u][3];
        }
    }
    float4 s;
    s.x = A[0].x + A[1].x + A[2].x + A[3].x;
    s.y = A[0].y + A[1].y + A[2].y + A[3].y;
    s.z = A[0].z + A[1].z + A[2].z + A[3].z;
    s.w = A[0].w + A[1].w + A[2].w + A[3].w;
    ushort4 o;
    o.x = f2h_(s.x); o.y = f2h_(s.y); o.z = f2h_(s.z); o.w = f2h_(s.w);
    *(ushort4*)(&T[ln * 72 + i4 * 4]) = o;       // T[node][feat], stride 72
    __syncthreads();
    // ---- phase B: layer 1, wave w handles N-tile nt = w ----
    int m = lane & 15, q = lane >> 4;
    const unsigned short* arow = &T[m * 72 + q * 8];
    hfrag A0 = *(const hfrag*)(arow);
    hfrag A1 = *(const hfrag*)(arow + 32);
    int nt = w;
    hfrag B0 = *(const hfrag*)(Wh1 + (((nt * 2 + 0) * 4 + q) * 16 + m) * 8);
    hfrag B1 = *(const hfrag*)(Wh1 + (((nt * 2 + 1) * 4 + q) * 16 + m) * 8);
    ffrag z = {0.f, 0.f, 0.f, 0.f};
    z = __builtin_amdgcn_mfma_f32_16x16x32_f16(A0, B0, z, 0, 0, 0);
    z = __builtin_amdgcn_mfma_f32_16x16x32_f16(A1, B1, z, 0, 0, 0);
    float b1n = Wbuf[4096 + nt * 16 + m];
    __syncthreads();                              // all A-frag reads of T done
#pragma unroll
    for (int r = 0; r < 4; ++r) {
        float hv = fmaxf(z[r] + b1n, 0.0f);
        T[(q * 4 + r) * 72 + nt * 16 + m] = f2h_(hv);
    }
    __syncthreads();
    // ---- phase C: layer 2 on wave 0 ----
    if (w == 0) {
        const unsigned short* hrow = &T[m * 72 + q * 8];
        hfrag H0 = *(const hfrag*)(hrow);
        hfrag H1 = *(const hfrag*)(hrow + 32);
        hfrag C0 = *(const hfrag*)(Wh2 + ((0 * 4 + q) * 16 + m) * 8);
        hfrag C1 = *(const hfrag*)(Wh2 + ((1 * 4 + q) * 16 + m) * 8);
        ffrag t2 = {0.f, 0.f, 0.f, 0.f};
        t2 = __builtin_amdgcn_mfma_f32_16x16x32_f16(H0, C0, t2, 0, 0, 0);
        t2 = __builtin_amdgcn_mfma_f32_16x16x32_f16(H1, C1, t2, 0, 0, 0);
#pragma unroll
        for (int r = 0; r < 4; ++r) {
            int nn = blockIdx.x * 16 + q * 4 + r;
            if (nn < N) t2b[(size_t)nn * 16 + m] = f2h_(t2[r]);
        }
    }
}

// ---- layer 2: gather T2 (fp16) + b2 + log_softmax -> out (8-deep pipeline) ----
__global__ __launch_bounds__(256) void k_l2(const unsigned short* __restrict__ t2b,
                                            const int* __restrict__ flags,
                                            const float* __restrict__ dis,
                                            const int2* __restrict__ row_se,
                                            const int* __restrict__ psr,
                                            const float* __restrict__ Wbuf,
                                            void* __restrict__ out, int N) {
    int isF32 = flags[0];
    int tid = threadIdx.x, lane = tid & 63;
    int g = lane >> 4, i = lane & 15;
    int n = blockIdx.x * 16 + (tid >> 6) * 4 + g;
    if (n >= N) return;
    float dd = dis[n];
    int2 se = row_se[n];
    int beg = se.x, end = se.y;
    int cnt = end - beg;
    float A[4];
    A[0] = dd * dd * h2f_(t2b[(size_t)n * 16 + i]);
    A[1] = 0.f; A[2] = 0.f; A[3] = 0.f;
    int T = (cnt + 7) >> 3;
    int p = beg;
    int e[8];
#pragma unroll
    for (int u = 0; u < 8; ++u) e[u] = psr[p + u];
    for (int t = 0; t < T; ++t) {
        float r[8], dv[8];
#pragma unroll
        for (int u = 0; u < 8; ++u) {
            unsigned ex = min((unsigned)e[u], (unsigned)(N - 1));
            r[u] = h2f_(t2b[(size_t)ex * 16 + i]);
            dv[u] = dis[ex];
        }
        float nv[8];
#pragma unroll
        for (int u = 0; u < 8; ++u) nv[u] = (p + u < end) ? dd * dv[u] : 0.f;
#pragma unroll
        for (int u = 0; u < 8; ++u) e[u] = psr[p + 8 + u];
        p += 8;
#pragma unroll
        for (int u = 0; u < 8; ++u) A[u & 3] += nv[u] * r[u];
    }
    float a0 = A[0] + A[1] + A[2] + A[3];
    float v = a0 + Wbuf[5184 + i];
    float mx = v;
#pragma unroll
    for (int off = 8; off; off >>= 1) mx = fmaxf(mx, __shfl_xor(mx, off, 16));
    float ex = __expf(v - mx);
    float ss = ex;
#pragma unroll
    for (int off = 8; off; off >>= 1) ss += __shfl_xor(ss, off, 16);
    float r = v - mx - logf(ss);
    size_t oi = (size_t)n * 16 + i;
    if (isF32) ((float*)out)[oi] = r;
    else       ((unsigned short*)out)[oi] = f2b_(r);
}

extern "C" void kernel_launch(void* const* d_in, const int* in_sizes, int n_in,
                              void* d_out, int out_size, void* d_ws, size_t ws_size,
                              hipStream_t stream) {
    const void* x  = d_in[0];
    const int*  ei = (const int*)d_in[1];
    const void* W1 = d_in[2];
    const void* b1 = d_in[3];
    const void* W2 = d_in[4];
    const void* b2 = d_in[5];

    const int N = in_sizes[0] / 64;     // 100000
    const int E = in_sizes[1] / 2;      // 1200000
    const int nbk = (N + LBS - 1) >> BSH;  // 391 coarse buckets
    const int EPB = (((E + NF - 1) / NF) + 7) & ~7;   // private slice size, 8-aligned

    // 64B-aligned workspace carving (~65 MB)
    char* p = (char*)d_ws;
#define CARVE(ty, name, bytes) ty name = (ty)p; p += (((size_t)(bytes)) + 63) & ~(size_t)63;
    CARVE(int*,   flags,     16)
    CARVE(float*, Wbuf,      5200 * 4)
    CARVE(unsigned short*, Wh1, 4096 * 2)
    CARVE(unsigned short*, Wh2, 1024 * 2)
    CARVE(float*, dis,       (size_t)N * 4)
    CARVE(int2*,  row_se,    (size_t)N * 8)
    CARVE(int*,   off_d,     (size_t)NF * OPAD * 4)
    CARVE(int*,   off_s,     (size_t)NF * OPAD * 4)
    CARVE(int*,   pdst,      (size_t)NF * EPB * 4)
    CARVE(unsigned char*, psrc, (size_t)NF * EPB)
    CARVE(int*,   psr,       (((size_t)nbk << CAP_SH) + 64) * 4)
    CARVE(unsigned short*, xh,   (size_t)N * 64 * 2)
    CARVE(unsigned short*, t2b,  (size_t)N * 16 * 2)
#undef CARVE

    k_stage<<<NF + 1 + CONV_BLKS, 256, 0, stream>>>(x, ei, W1, b1, W2, b2,
                                                    E, N, nbk, EPB,
                                                    flags, Wbuf, Wh1, Wh2,
                                                    off_d, off_s, pdst, psrc, xh);
    k_degcsr<<<nbk, 512, 0, stream>>>(psrc, pdst, off_s, off_d, dis, row_se, psr, N, nbk);
    k_aggdense<<<(N + 15) / 16, 256, 0, stream>>>(xh, dis, row_se, psr,
                                                  Wh1, Wh2, Wbuf, t2b, N);
    k_l2<<<(N + 15) / 16, 256, 0, stream>>>(t2b, flags, dis, row_se, psr, Wbuf, d_out, N);
}

// Round 15
// 178.212 us; speedup vs baseline: 4.3639x; 1.0148x over previous
//
#include <hip/hip_runtime.h>
#include <hip/hip_bf16.h>

typedef __attribute__((ext_vector_type(8))) _Float16 hfrag;
typedef __attribute__((ext_vector_type(4))) float ffrag;
typedef __attribute__((ext_vector_type(4))) _Float16 h4v;

// bucket = 256 consecutive nodes; supports N <= 131072 (static LDS hist arrays)
#define BSH 8
#define LBS 256
#define CAP_SH 14              // 16384-slot padded psr region per bucket
#define CAP (1 << CAP_SH)
#define NF 512                 // edge partitions
#define OPAD 520               // row stride of the fragment-offset tables (> nbk max 512)
#define CONV_BLKS 384
#define EPBC 4096              // LDS edge-staging capacity in k_stage
#define ELC 4096               // LDS bucket-edge capacity in k_degcsr (mean 3070)

__device__ __forceinline__ float b2f_(unsigned short u) {
    return __uint_as_float(((unsigned)u) << 16);
}
__device__ __forceinline__ unsigned short f2b_(float v) {
    __hip_bfloat16 h = __float2bfloat16(v);   // RNE
    return *reinterpret_cast<unsigned short*>(&h);
}
__device__ __forceinline__ unsigned short f2h_(float v) {
    _Float16 h = (_Float16)v;                 // RNE
    return __builtin_bit_cast(unsigned short, h);
}
__device__ __forceinline__ float h2f_(unsigned short u) {
    _Float16 h = __builtin_bit_cast(_Float16, u);
    return (float)h;
}

__device__ __forceinline__ float loadF(const void* p, long long i, int isF32) {
    if (isF32) return ((const float*)p)[i];
    return b2f_(((const unsigned short*)p)[i]);
}

__device__ __forceinline__ float4 loadF4(const void* p, long long base, int i4, int isF32) {
    if (isF32) {
        return ((const float4*)((const float*)p + base))[i4];
    } else {
        ushort4 u = ((const ushort4*)((const unsigned short*)p + base))[i4];
        return make_float4(b2f_(u.x), b2f_(u.y), b2f_(u.z), b2f_(u.w));
    }
}

__device__ __forceinline__ void get_edge(const int* ei, int i64, int e, int E, int& s, int& d) {
    if (i64) { s = ei[2 * (long long)e]; d = ei[2 * (long long)E + 2 * (long long)e]; }
    else     { s = ei[e];                d = ei[(long long)E + e]; }
}

// batch-load 4 edges (srcs+dsts) with int4 vector loads; e0 multiple of 4
struct E4 { int s[4]; int d[4]; };
__device__ __forceinline__ E4 load4(const int* __restrict__ ei, int i64, int e0, int E) {
    E4 r;
    if (i64) {
        const int4* ps = (const int4*)(ei + 2 * (long long)e0);
        const int4* pd = (const int4*)(ei + 2 * (long long)E + 2 * (long long)e0);
        int4 a = ps[0], b = ps[1];
        int4 c = pd[0], d = pd[1];
        r.s[0] = a.x; r.s[1] = a.z; r.s[2] = b.x; r.s[3] = b.z;
        r.d[0] = c.x; r.d[1] = c.z; r.d[2] = d.x; r.d[3] = d.z;
    } else {
        int4 a = *(const int4*)(ei + e0);
        int4 c = *(const int4*)(ei + (long long)E + e0);
        r.s[0] = a.x; r.s[1] = a.y; r.s[2] = a.z; r.s[3] = a.w;
        r.d[0] = c.x; r.d[1] = c.y; r.d[2] = c.z; r.d[3] = c.w;
    }
    return r;
}

// exclusive scan of a[0..nEl) in LDS by ONE wave (lane = 0..63), chunked shuffle scan
__device__ __forceinline__ void wave_scan_excl(int* a, int nEl, int lane) {
    int run = 0;
    for (int base = 0; base < nEl; base += 64) {
        int i = base + lane;
        int orig = (i < nEl) ? a[i] : 0;
        int v = orig;
#pragma unroll
        for (int off = 1; off < 64; off <<= 1) {
            int u = __shfl_up(v, off);
            if (lane >= off) v += u;
        }
        if (i < nEl) a[i] = v - orig + run;
        run += __shfl(v, 63);
    }
}

// ---- S1 (single staging kernel, fully independent blocks):
//   blocks [0,NF): ONE global sweep — slice staged in LDS, then hist/scan/scatter
//     from LDS into a PRIVATE output window.
//   block NF: dtype detect + flags + weight conversion + fp16 MFMA-fragment pack.
//   blocks > NF: x -> fp16 conversion (locally re-derived dtype flag). ----
__global__ __launch_bounds__(256) void k_stage(const void* __restrict__ x,
                                               const int* __restrict__ ei,
                                               const void* __restrict__ W1, const void* __restrict__ b1,
                                               const void* __restrict__ W2, const void* __restrict__ b2,
                                               int E, int N, int nbk, int EPB,
                                               int* __restrict__ flags, float* __restrict__ Wbuf,
                                               unsigned short* __restrict__ Wh1,
                                               unsigned short* __restrict__ Wh2,
                                               int* __restrict__ off_d, int* __restrict__ off_s,
                                               int* __restrict__ pdst,
                                               unsigned char* __restrict__ psrc,
                                               unsigned short* __restrict__ xh) {
    __shared__ int hd[512], hs[512], cd[512], cs[512];
    __shared__ int es[EPBC], ed[EPBC];   // LDS edge staging (32 KB)
    __shared__ int s_sane, s_zero;
    int tid = threadIdx.x;
    if (tid == 0) { s_sane = 0; s_zero = 0; }
    __syncthreads();
    const unsigned short* xu = (const unsigned short*)x;
    if (blockIdx.x == NF) {
        int sane = 0;
        for (int k = tid; k < 4096; k += 256) {
            float v = b2f_(xu[2 * k]);
            float a = fabsf(v);
            if (v == 0.0f || (a >= 9.3e-10f && a <= 1.1e9f)) sane++;
        }
        if (sane) atomicAdd(&s_sane, sane);
        int zero = 0;
        for (int k = tid; k < 1024; k += 256) if (ei[2 * k + 1] == 0) zero++;
        if (zero) atomicAdd(&s_zero, zero);
        __syncthreads();
        int f = (s_sane < 3000) ? 1 : 0;   // 1 = f32 input
        if (tid == 0) { flags[0] = f; flags[1] = (s_zero > 512) ? 1 : 0; }
        for (int i = tid; i < 4096; i += 256) Wbuf[i] = loadF(W1, i, f);
        if (tid < 64) Wbuf[4096 + tid] = loadF(b1, tid, f);
        for (int i = tid; i < 1024; i += 256) Wbuf[4160 + i] = loadF(W2, i, f);
        if (tid < 16) Wbuf[5184 + tid] = loadF(b2, tid, f);
        __syncthreads();
        // pack W1/W2 into fp16 MFMA B-fragment order
        for (int i = tid; i < 4096; i += 256) {
            int j = i & 7, m = (i >> 3) & 15, q = (i >> 7) & 3, kn = i >> 9;
            int kt = kn & 1, nt = kn >> 1;
            Wh1[i] = f2h_(Wbuf[(kt * 32 + q * 8 + j) * 64 + nt * 16 + m]);
        }
        for (int i = tid; i < 1024; i += 256) {
            int j = i & 7, m = (i >> 3) & 15, q = (i >> 7) & 3, kt = i >> 9;
            Wh2[i] = f2h_(Wbuf[4160 + (kt * 32 + q * 8 + j) * 16 + m]);
        }
        return;
    }
    if (blockIdx.x > NF) {
        // ---- conv block: local dtype re-derivation (L2-hot), then x->fp16 ----
        int cb = blockIdx.x - NF - 1;
        int sane = 0;
        for (int k = tid; k < 4096; k += 256) {
            float v = b2f_(xu[2 * k]);
            float a = fabsf(v);
            if (v == 0.0f || (a >= 9.3e-10f && a <= 1.1e9f)) sane++;
        }
        if (sane) atomicAdd(&s_sane, sane);
        __syncthreads();
        int f = (s_sane < 3000) ? 1 : 0;
        int n4 = N * 16;   // float4-groups
        int ctid = cb * 256 + tid;
        int stride = CONV_BLKS * 256 * 2;
        for (int i0 = ctid * 2; i0 < n4; i0 += stride) {
            float4 v0 = loadF4(x, 0, i0, f);
            float4 v1 = (i0 + 1 < n4) ? loadF4(x, 0, i0 + 1, f) : make_float4(0, 0, 0, 0);
            ushort4 o0, o1;
            o0.x = f2h_(v0.x); o0.y = f2h_(v0.y); o0.z = f2h_(v0.z); o0.w = f2h_(v0.w);
            o1.x = f2h_(v1.x); o1.y = f2h_(v1.y); o1.z = f2h_(v1.z); o1.w = f2h_(v1.w);
            ((ushort4*)xh)[i0] = o0;
            if (i0 + 1 < n4) ((ushort4*)xh)[i0 + 1] = o1;
        }
        return;
    }
    // ---- edge block fb: private slice [elo, ehi), private window [elo, elo+ecnt) ----
    int zero = 0;
    for (int k = tid; k < 1024; k += 256) if (ei[2 * k + 1] == 0) zero++;
    if (zero) atomicAdd(&s_zero, zero);
    for (int i = tid; i < 512; i += 256) { hd[i] = 0; hs[i] = 0; }
    __syncthreads();
    int i64 = (s_zero > 512) ? 1 : 0;
    int fb = blockIdx.x;
    int elo = fb * EPB;
    int ehi = min(elo + EPB, E);
    if (elo >= E) {    // empty slice: still publish (empty) fragment offsets
        for (int b = tid; b <= nbk; b += 256) {
            off_d[fb * OPAD + b] = E; off_s[fb * OPAD + b] = E;
        }
        return;
    }
    int ecnt = ehi - elo;
    int rem = ecnt & 3, ebase = elo + (ecnt & ~3);
    if (ecnt <= EPBC) {
        // ---- single global sweep: stage slice in LDS ----
        for (int e0 = elo + tid * 4; e0 + 4 <= ehi; e0 += 1024) {
            E4 a = load4(ei, i64, e0, E);
            int base = e0 - elo;
#pragma unroll
            for (int u = 0; u < 4; ++u) { es[base + u] = a.s[u]; ed[base + u] = a.d[u]; }
        }
        if (tid < rem) {
            int s, d;
            get_edge(ei, i64, ebase + tid, E, s, d);
            es[ecnt - rem + tid] = s; ed[ecnt - rem + tid] = d;
        }
        __syncthreads();
        // hist from LDS
        for (int i = tid; i < ecnt; i += 256) {
            atomicAdd(&hd[ed[i] >> BSH], 1);
            atomicAdd(&hs[es[i] >> BSH], 1);
        }
        __syncthreads();
        if (tid < 64)       wave_scan_excl(hd, nbk, tid);
        else if (tid < 128) wave_scan_excl(hs, nbk, tid - 64);
        __syncthreads();
        for (int b = tid; b < nbk; b += 256) {
            int od = elo + hd[b], os = elo + hs[b];
            off_d[fb * OPAD + b] = od; cd[b] = od;
            off_s[fb * OPAD + b] = os; cs[b] = os;
        }
        if (tid == 0) { off_d[fb * OPAD + nbk] = elo + ecnt; off_s[fb * OPAD + nbk] = elo + ecnt; }
        __syncthreads();
        // scatter from LDS
        for (int i = tid; i < ecnt; i += 256) {
            int s = es[i], d = ed[i];
            int p = atomicAdd(&cd[d >> BSH], 1);
            pdst[p] = (s << BSH) | (d & (LBS - 1));
            int q = atomicAdd(&cs[s >> BSH], 1);
            psrc[q] = (unsigned char)(s & (LBS - 1));
        }
        return;
    }
    // ---- fallback: two global sweeps (slice too large for LDS) ----
    for (int e0 = elo + tid * 4; e0 + 4 <= ehi; e0 += 1024) {
        E4 a = load4(ei, i64, e0, E);
#pragma unroll
        for (int u = 0; u < 4; ++u) {
            atomicAdd(&hd[a.d[u] >> BSH], 1);
            atomicAdd(&hs[a.s[u] >> BSH], 1);
        }
    }
    if (tid < rem) {
        int s, d;
        get_edge(ei, i64, ebase + tid, E, s, d);
        atomicAdd(&hd[d >> BSH], 1);
        atomicAdd(&hs[s >> BSH], 1);
    }
    __syncthreads();
    if (tid < 64)       wave_scan_excl(hd, nbk, tid);
    else if (tid < 128) wave_scan_excl(hs, nbk, tid - 64);
    __syncthreads();
    for (int b = tid; b < nbk; b += 256) {
        int od = elo + hd[b], os = elo + hs[b];
        off_d[fb * OPAD + b] = od; cd[b] = od;
        off_s[fb * OPAD + b] = os; cs[b] = os;
    }
    if (tid == 0) { off_d[fb * OPAD + nbk] = elo + ecnt; off_s[fb * OPAD + nbk] = elo + ecnt; }
    __syncthreads();
    for (int e0 = elo + tid * 4; e0 + 4 <= ehi; e0 += 1024) {
        E4 a = load4(ei, i64, e0, E);
#pragma unroll
        for (int u = 0; u < 4; ++u) {
            int p = atomicAdd(&cd[a.d[u] >> BSH], 1);
            pdst[p] = (a.s[u] << BSH) | (a.d[u] & (LBS - 1));
            int q = atomicAdd(&cs[a.s[u] >> BSH], 1);
            psrc[q] = (unsigned char)(a.s[u] & (LBS - 1));
        }
    }
    if (tid < rem) {
        int s, d;
        get_edge(ei, i64, ebase + tid, E, s, d);
        int p = atomicAdd(&cd[d >> BSH], 1);
        pdst[p] = (s << BSH) | (d & (LBS - 1));
        int q = atomicAdd(&cs[s >> BSH], 1);
        psrc[q] = (unsigned char)(s & (LBS - 1));
    }
}

// ---- C2 (fused deg + csr, one block per bucket, 512 threads):
//   phase 1: src-degree hist from psrc fragments -> dis = rsqrt(deg+1)
//   phase 2: compact dst fragments into LDS (ONE walk + ONE pdst pass), then
//            hist/scan/scatter from LDS -> rdesc{beg,end,dis} + psr. ----
__global__ __launch_bounds__(512) void k_degcsr(const unsigned char* __restrict__ psrc,
                                                const int* __restrict__ pdst,
                                                const int* __restrict__ off_s,
                                                const int* __restrict__ off_d,
                                                float* __restrict__ dis,
                                                int4* __restrict__ rdesc,
                                                int* __restrict__ psr, int N, int nbk) {
    __shared__ int elist[ELC];           // 16 KB
    __shared__ int h[LBS], lb[LBS], cur[LBS];
    __shared__ float dloc[LBS];
    __shared__ int s_cnt;
    int b = blockIdx.x, tid = threadIdx.x;
    if (tid == 0) s_cnt = 0;
    if (tid < LBS) h[tid] = 0;
    __syncthreads();
    // phase 1: src-degree hist (single fragment walk)
    for (int fb = tid; fb < NF; fb += 512) {
        int o0 = off_s[fb * OPAD + b];
        int o1 = off_s[fb * OPAD + b + 1];
        for (int p = o0; p < o1; ++p) atomicAdd(&h[psrc[p]], 1);
    }
    __syncthreads();
    if (tid < LBS) {
        float dv = rsqrtf((float)h[tid] + 1.0f);
        dloc[tid] = dv;
        int node = b * LBS + tid;
        if (node < N) dis[node] = dv;
    }
    __syncthreads();
    if (tid < LBS) h[tid] = 0;
    __syncthreads();
    // phase 2a: compact dst fragments into LDS (the ONLY off_d walk)
    for (int fb = tid; fb < NF; fb += 512) {
        int o0 = off_d[fb * OPAD + b];
        int o1 = off_d[fb * OPAD + b + 1];
        int len = o1 - o0;
        if (len > 0) {
            int base = atomicAdd(&s_cnt, len);
            for (int k = 0; k < len; ++k)
                if (base + k < ELC) elist[base + k] = pdst[o0 + k];
        }
    }
    __syncthreads();
    int cnt = s_cnt;
    int beg = b << CAP_SH;
    if (cnt <= ELC) {
        // phase 2b: hist + scan + scatter entirely from LDS
        for (int i = tid; i < cnt; i += 512) atomicAdd(&h[elist[i] & (LBS - 1)], 1);
        __syncthreads();
        if (tid < LBS) lb[tid] = h[tid];
        __syncthreads();
        if (tid < 64) wave_scan_excl(lb, LBS, tid);
        __syncthreads();
        if (tid < LBS) {
            cur[tid] = lb[tid];
            int node = b * LBS + tid;
            if (node < N) {
                int s0 = min(lb[tid], CAP), s1 = min(lb[tid] + h[tid], CAP);
                rdesc[node] = make_int4(beg + s0, beg + s1, __float_as_int(dloc[tid]), 0);
            }
        }
        __syncthreads();
        for (int i = tid; i < cnt; i += 512) {
            int e = elist[i];
            int r = atomicAdd(&cur[e & (LBS - 1)], 1);
            if (r < CAP) psr[beg + r] = e >> BSH;
        }
        return;
    }
    // ---- fallback: 2-pass global walks (bucket overflow) ----
    if (tid < LBS) h[tid] = 0;
    __syncthreads();
    for (int fb = tid; fb < NF; fb += 512) {
        int o0 = off_d[fb * OPAD + b];
        int o1 = off_d[fb * OPAD + b + 1];
        for (int p = o0; p < o1; ++p) atomicAdd(&h[pdst[p] & (LBS - 1)], 1);
    }
    __syncthreads();
    if (tid < LBS) lb[tid] = h[tid];
    __syncthreads();
    if (tid < 64) wave_scan_excl(lb, LBS, tid);
    __syncthreads();
    if (tid < LBS) {
        cur[tid] = lb[tid];
        int node = b * LBS + tid;
        if (node < N) {
            int s0 = min(lb[tid], CAP), s1 = min(lb[tid] + h[tid], CAP);
            rdesc[node] = make_int4(beg + s0, beg + s1, __float_as_int(dloc[tid]), 0);
        }
    }
    __syncthreads();
    for (int fb = tid; fb < NF; fb += 512) {
        int o0 = off_d[fb * OPAD + b];
        int o1 = off_d[fb * OPAD + b + 1];
        for (int p = o0; p < o1; ++p) {
            int e = pdst[p];
            int r = atomicAdd(&cur[e & (LBS - 1)], 1);
            if (r < CAP) psr[beg + r] = e >> BSH;
        }
    }
}

// ---- fused aggregation + dense chain (16-node block = 4 waves x 4 nodes):
//   phase A: AGG via 8-deep gather pipeline (rdesc one-load prologue) -> fp16 tile
//   phase B: layer1 MFMA -> relu+bias -> H in LDS (reused)
//   phase C: layer2 MFMA (wave 0) -> t2b ----
__global__ __launch_bounds__(256) void k_aggdense(const unsigned short* __restrict__ xh,
                                                  const float* __restrict__ dis,
                                                  const int4* __restrict__ rdesc,
                                                  const int* __restrict__ psr,
                                                  const unsigned short* __restrict__ Wh1,
                                                  const unsigned short* __restrict__ Wh2,
                                                  const float* __restrict__ Wbuf,
                                                  unsigned short* __restrict__ t2b, int N) {
    __shared__ __align__(16) unsigned short T[16 * 72];
    int tid = threadIdx.x;
    int lane = tid & 63;
    int w = tid >> 6;
    int g = lane >> 4, i4 = lane & 15;
    int ln = w * 4 + g;                      // local node 0..15
    int n = blockIdx.x * 16 + ln;
    int act = (n < N);
    float4 A[4];
#pragma unroll
    for (int u = 0; u < 4; ++u) A[u] = make_float4(0.f, 0.f, 0.f, 0.f);
    float dd = 0.f;
    int beg = 0, end = 0;
    if (act) {
        int4 rd = rdesc[n];                 // ONE load: {beg, end, dis}
        beg = rd.x; end = rd.y; dd = __int_as_float(rd.z);
        h4v xv = *(const h4v*)(xh + (long long)n * 64 + i4 * 4);
        float ww = dd * dd;
        A[0].x = ww * (float)xv[0]; A[0].y = ww * (float)xv[1];
        A[0].z = ww * (float)xv[2]; A[0].w = ww * (float)xv[3];
    }
    int cnt = end - beg;
    int Tn = (cnt + 7) >> 3;
    int p = beg;
    int e[8];
#pragma unroll
    for (int u = 0; u < 8; ++u) e[u] = psr[p + u];
    for (int t = 0; t < Tn; ++t) {
        h4v hv[8];
        float dv[8];
#pragma unroll
        for (int u = 0; u < 8; ++u) {
            unsigned ex = min((unsigned)e[u], (unsigned)(N - 1));
            hv[u] = *(const h4v*)(xh + (long long)ex * 64 + i4 * 4);
            dv[u] = dis[ex];
        }
        float nv[8];
#pragma unroll
        for (int u = 0; u < 8; ++u) nv[u] = (p + u < end) ? dd * dv[u] : 0.f;
#pragma unroll
        for (int u = 0; u < 8; ++u) e[u] = psr[p + 8 + u];
        p += 8;
#pragma unroll
        for (int u = 0; u < 8; ++u) {
            A[u & 3].x += nv[u] * (float)hv[u][0];
            A[u & 3].y += nv[u] * (float)hv[u][1];
            A[u & 3].z += nv[u] * (float)hv[u][2];
            A[u & 3].w += nv[u] * (float)hv[u][3];
        }
    }
    float4 s;
    s.x = A[0].x + A[1].x + A[2].x + A[3].x;
    s.y = A[0].y + A[1].y + A[2].y + A[3].y;
    s.z = A[0].z + A[1].z + A[2].z + A[3].z;
    s.w = A[0].w + A[1].w + A[2].w + A[3].w;
    ushort4 o;
    o.x = f2h_(s.x); o.y = f2h_(s.y); o.z = f2h_(s.z); o.w = f2h_(s.w);
    *(ushort4*)(&T[ln * 72 + i4 * 4]) = o;       // T[node][feat], stride 72
    __syncthreads();
    // ---- phase B: layer 1, wave w handles N-tile nt = w ----
    int m = lane & 15, q = lane >> 4;
    const unsigned short* arow = &T[m * 72 + q * 8];
    hfrag A0 = *(const hfrag*)(arow);
    hfrag A1 = *(const hfrag*)(arow + 32);
    int nt = w;
    hfrag B0 = *(const hfrag*)(Wh1 + (((nt * 2 + 0) * 4 + q) * 16 + m) * 8);
    hfrag B1 = *(const hfrag*)(Wh1 + (((nt * 2 + 1) * 4 + q) * 16 + m) * 8);
    ffrag z = {0.f, 0.f, 0.f, 0.f};
    z = __builtin_amdgcn_mfma_f32_16x16x32_f16(A0, B0, z, 0, 0, 0);
    z = __builtin_amdgcn_mfma_f32_16x16x32_f16(A1, B1, z, 0, 0, 0);
    float b1n = Wbuf[4096 + nt * 16 + m];
    __syncthreads();                              // all A-frag reads of T done
#pragma unroll
    for (int r = 0; r < 4; ++r) {
        float hv = fmaxf(z[r] + b1n, 0.0f);
        T[(q * 4 + r) * 72 + nt * 16 + m] = f2h_(hv);
    }
    __syncthreads();
    // ---- phase C: layer 2 on wave 0 ----
    if (w == 0) {
        const unsigned short* hrow = &T[m * 72 + q * 8];
        hfrag H0 = *(const hfrag*)(hrow);
        hfrag H1 = *(const hfrag*)(hrow + 32);
        hfrag C0 = *(const hfrag*)(Wh2 + ((0 * 4 + q) * 16 + m) * 8);
        hfrag C1 = *(const hfrag*)(Wh2 + ((1 * 4 + q) * 16 + m) * 8);
        ffrag t2 = {0.f, 0.f, 0.f, 0.f};
        t2 = __builtin_amdgcn_mfma_f32_16x16x32_f16(H0, C0, t2, 0, 0, 0);
        t2 = __builtin_amdgcn_mfma_f32_16x16x32_f16(H1, C1, t2, 0, 0, 0);
#pragma unroll
        for (int r = 0; r < 4; ++r) {
            int nn = blockIdx.x * 16 + q * 4 + r;
            if (nn < N) t2b[(size_t)nn * 16 + m] = f2h_(t2[r]);
        }
    }
}

// ---- layer 2: gather T2 (fp16) + b2 + log_softmax -> out (8-deep pipeline) ----
__global__ __launch_bounds__(256) void k_l2(const unsigned short* __restrict__ t2b,
                                            const int* __restrict__ flags,
                                            const float* __restrict__ dis,
                                            const int4* __restrict__ rdesc,
                                            const int* __restrict__ psr,
                                            const float* __restrict__ Wbuf,
                                            void* __restrict__ out, int N) {
    int isF32 = flags[0];
    int tid = threadIdx.x, lane = tid & 63;
    int g = lane >> 4, i = lane & 15;
    int n = blockIdx.x * 16 + (tid >> 6) * 4 + g;
    if (n >= N) return;
    int4 rd = rdesc[n];                      // ONE load: {beg, end, dis}
    int beg = rd.x, end = rd.y;
    float dd = __int_as_float(rd.z);
    int cnt = end - beg;
    float A[4];
    A[0] = dd * dd * h2f_(t2b[(size_t)n * 16 + i]);
    A[1] = 0.f; A[2] = 0.f; A[3] = 0.f;
    int T = (cnt + 7) >> 3;
    int p = beg;
    int e[8];
#pragma unroll
    for (int u = 0; u < 8; ++u) e[u] = psr[p + u];
    for (int t = 0; t < T; ++t) {
        float r[8], dv[8];
#pragma unroll
        for (int u = 0; u < 8; ++u) {
            unsigned ex = min((unsigned)e[u], (unsigned)(N - 1));
            r[u] = h2f_(t2b[(size_t)ex * 16 + i]);
            dv[u] = dis[ex];
        }
        float nv[8];
#pragma unroll
        for (int u = 0; u < 8; ++u) nv[u] = (p + u < end) ? dd * dv[u] : 0.f;
#pragma unroll
        for (int u = 0; u < 8; ++u) e[u] = psr[p + 8 + u];
        p += 8;
#pragma unroll
        for (int u = 0; u < 8; ++u) A[u & 3] += nv[u] * r[u];
    }
    float a0 = A[0] + A[1] + A[2] + A[3];
    float v = a0 + Wbuf[5184 + i];
    float mx = v;
#pragma unroll
    for (int off = 8; off; off >>= 1) mx = fmaxf(mx, __shfl_xor(mx, off, 16));
    float ex = __expf(v - mx);
    float ss = ex;
#pragma unroll
    for (int off = 8; off; off >>= 1) ss += __shfl_xor(ss, off, 16);
    float r = v - mx - logf(ss);
    size_t oi = (size_t)n * 16 + i;
    if (isF32) ((float*)out)[oi] = r;
    else       ((unsigned short*)out)[oi] = f2b_(r);
}

extern "C" void kernel_launch(void* const* d_in, const int* in_sizes, int n_in,
                              void* d_out, int out_size, void* d_ws, size_t ws_size,
                              hipStream_t stream) {
    const void* x  = d_in[0];
    const int*  ei = (const int*)d_in[1];
    const void* W1 = d_in[2];
    const void* b1 = d_in[3];
    const void* W2 = d_in[4];
    const void* b2 = d_in[5];

    const int N = in_sizes[0] / 64;     // 100000
    const int E = in_sizes[1] / 2;      // 1200000
    const int nbk = (N + LBS - 1) >> BSH;  // 391 coarse buckets
    const int EPB = (((E + NF - 1) / NF) + 7) & ~7;   // private slice size, 8-aligned

    // 64B-aligned workspace carving (~66 MB)
    char* p = (char*)d_ws;
#define CARVE(ty, name, bytes) ty name = (ty)p; p += (((size_t)(bytes)) + 63) & ~(size_t)63;
    CARVE(int*,   flags,     16)
    CARVE(float*, Wbuf,      5200 * 4)
    CARVE(unsigned short*, Wh1, 4096 * 2)
    CARVE(unsigned short*, Wh2, 1024 * 2)
    CARVE(float*, dis,       (size_t)N * 4)
    CARVE(int4*,  rdesc,     (size_t)N * 16)
    CARVE(int*,   off_d,     (size_t)NF * OPAD * 4)
    CARVE(int*,   off_s,     (size_t)NF * OPAD * 4)
    CARVE(int*,   pdst,      (size_t)NF * EPB * 4)
    CARVE(unsigned char*, psrc, (size_t)NF * EPB)
    CARVE(int*,   psr,       (((size_t)nbk << CAP_SH) + 64) * 4)
    CARVE(unsigned short*, xh,   (size_t)N * 64 * 2)
    CARVE(unsigned short*, t2b,  (size_t)N * 16 * 2)
#undef CARVE

    k_stage<<<NF + 1 + CONV_BLKS, 256, 0, stream>>>(x, ei, W1, b1, W2, b2,
                                                    E, N, nbk, EPB,
                                                    flags, Wbuf, Wh1, Wh2,
                                                    off_d, off_s, pdst, psrc, xh);
    k_degcsr<<<nbk, 512, 0, stream>>>(psrc, pdst, off_s, off_d, dis, rdesc, psr, N, nbk);
    k_aggdense<<<(N + 15) / 16, 256, 0, stream>>>(xh, dis, rdesc, psr,
                                                  Wh1, Wh2, Wbuf, t2b, N);
    k_l2<<<(N + 15) / 16, 256, 0, stream>>>(t2b, flags, dis, rdesc, psr, Wbuf, d_out, N);
}